// Round 7
// baseline (177.240 us; speedup 1.0000x reference)
//
#include <hip/hip_runtime.h>
#include <hip/hip_bf16.h>
#include <stdint.h>

// ---------------------------------------------------------------------------
// TensorNet: fused encoder MLP (128->256->256->256, relu) over 32x4096 tokens,
// per-batch mean -> p = relu(m^2) -> decoder MLP (256->512->512->10).
//
// R22: break the VGPR-64 occupancy cliff. Evidence across R12-R21: measured
// resident waves pin at ~9/CU whenever VGPR in (64,128] — the hardware
// waves/SIMD caps are 8 @ <=64 VGPR, 4 @ <=128, 2 @ <=256 (m69); LDS was
// never binding after R17 (16KB vs 32KB made zero occupancy difference,
// R21). A 64-reg accumulator forbids VGPR<=64 at 4 waves/block, so:
// 512-thread blocks, 8 waves, wave owns 32 hidden x 64 tokens ->
// acc[2][4]=32 VGPRs; live-set ~55-60; __launch_bounds__(512,8) pins
// VGPR=64 (bound ~= live-set, unlike R5/R19 where bound << live-set ->
// spills; watch WRITE_SIZE). Same NBLK=2048, same total a-traffic
// (16 jt-slices/block); b-reads double (LDS pipe has headroom).
// fp8 e4m3 layers 2/3 kept from R21 (absmax unchanged = layout verified);
// epilogue atomics re-coalesced via 1KB scratch (R21's 16x atomic instr
// count is the prime suspect for its +9us vs R17).
//
// HARD RULES from the log:
//  - launch_bounds min-waves ONLY when bound >= live-set estimate
//    (R5/R19: bound far below live-set -> catastrophic spills).
//  - NEVER grow per-wave a-load count for "sharing" (R18: 185us).
//  - NEVER shrink MTILE / grow block count (R20: +34% blocks, no gain).
// Rejected: MTILE=128 (R16), MTILE=48 (R20), wave->token remap (R18),
// direct-global B-frags (R5/R6), ping-pong (R13), cooperative (R11),
// decoder-in-encoder (R14/R15).
// ---------------------------------------------------------------------------

#define NIN   128
#define NHID  256
#define NDEC  512
#define NOUTC 10
#define BATCH 32
#define NTOK  4096
#define MTILE 64
#define NBLK  (BATCH * (NTOK / MTILE))   // 2048 encoder tiles

#define SWZ(t) (((t) & 7) << 4)          // XOR swizzle, byte bits 4-6

typedef short bf16x8 __attribute__((ext_vector_type(8)));
typedef float floatx4 __attribute__((ext_vector_type(4)));

__device__ __forceinline__ uint16_t f2b(float f) {
  union { uint32_t u; float f; } v; v.f = f;
  uint32_t r = v.u + 0x7FFFu + ((v.u >> 16) & 1u);   // RNE
  return (uint16_t)(r >> 16);
}
__device__ __forceinline__ uint32_t pkbf(float lo, float hi) {
  __hip_bfloat162 h = __float22bfloat162_rn(float2{lo, hi});  // v_cvt_pk_bf16_f32
  union { __hip_bfloat162 h; uint32_t u; } c; c.h = h;
  return c.u;
}

// ---------------------------------------------------------------------------
// Pack weights into MFMA-A-fragment order: W1 -> bf16 (bytes [0,64K)),
// W2/W3 -> fp8 e4m3 ([64K,128K) / [128K,192K)). Also zero-inits msum and
// pre-loads out with c3 (decoder atomics accumulate; stream-ordered).
// ---------------------------------------------------------------------------
__global__ __launch_bounds__(256) void pack_weights(
    const float* __restrict__ W1, const float* __restrict__ W2,
    const float* __restrict__ W3, const float* __restrict__ c3,
    uint8_t* __restrict__ pW, float* __restrict__ msum,
    float* __restrict__ out) {
  int p = blockIdx.x * blockDim.x + threadIdx.x;
  if (p < BATCH * NHID) msum[p] = 0.f;
  if (p < BATCH * NOUTC) out[p] = c3[p % NOUTC];
  if (p < 32768) {
    // W1: K=128, KC=4, bf16
    int j = p & 7, ln = (p >> 3) & 63, rest = p >> 9;
    int kc = rest & 3, mt = rest >> 2;
    int m = mt * 16 + (ln & 15);
    int k = kc * 32 + ((ln >> 4) << 3) + j;
    ((uint16_t*)pW)[p] = f2b(W1[k * NHID + m]);
  } else {
    int p2 = p - 32768;
    const float* W = (p2 < 65536) ? W2 : W3;
    int base = (p2 < 65536) ? 65536 : 131072;
    if (p2 >= 65536) p2 -= 65536;
    // K=256, KC=8, fp8 e4m3
    int j = p2 & 7, ln = (p2 >> 3) & 63, rest = p2 >> 9;
    int kc = rest & 7, mt = rest >> 3;
    int m = mt * 16 + (ln & 15);
    int k = kc * 32 + ((ln >> 4) << 3) + j;
    int r = __builtin_amdgcn_cvt_pk_fp8_f32(W[k * NHID + m], 0.f, 0, false);
    pW[base + p2] = (uint8_t)(r & 0xFF);
  }
}

// ---------------------------------------------------------------------------
// Fused encoder. Block = 512 thr (8 waves), 64 tokens. Wave w owns hidden
// rows [32w,32w+32) (jt=0..1); acc[2][4] = 32 VGPRs. LDS: 16KB tile + 1KB
// scratch. VGPR pinned to 64 -> 8 waves/SIMD cap -> up to 4 blocks (32
// waves)/CU.
// ---------------------------------------------------------------------------
__global__ __launch_bounds__(512, 8) void encoder(
    const float* __restrict__ x,        // [BATCH*NTOK][NIN] fp32
    const uint8_t* __restrict__ pW,
    const float* __restrict__ b1,
    const float* __restrict__ b2,
    const float* __restrict__ b3,
    float* __restrict__ msum) {         // [BATCH][NHID] fp32 accum
  __shared__ __align__(16) uint8_t Hs[MTILE * 256];   // 16384 B
  __shared__ __align__(16) float scr[NHID];           // 1024 B

  const int tid  = threadIdx.x;
  const int wave = tid >> 6;
  const int lane = tid & 63;
  const int l15  = lane & 15;
  const int q    = lane >> 4;
  const int tok0  = blockIdx.x * MTILE;
  const int batch = blockIdx.x >> 6;          // 64 tiles per batch

  const uint16_t* pW1 = (const uint16_t*)pW;  // bf16 frags, KC=4
  const uint8_t*  pW2 = pW + 65536;           // fp8 frags, KC=8
  const uint8_t*  pW3 = pW + 131072;          // fp8 frags, KC=8

  // ---- stage x tile: 64 tokens x 128 ch fp32 -> bf16, row stride 256B ----
  {
    const float4* xv = (const float4*)(x + (size_t)tok0 * NIN);
#pragma unroll
    for (int i = 0; i < 2; ++i) {
      const int u = tid + i * 512;            // 8-float unit, 0..1023
      float4 va = xv[2 * u];
      float4 vb = xv[2 * u + 1];
      uint4 w = make_uint4(pkbf(va.x, va.y), pkbf(va.z, va.w),
                           pkbf(vb.x, vb.y), pkbf(vb.z, vb.w));
      const int row = u >> 4;                 // token 0..63
      const int cb  = (u & 15) << 4;          // byte col 0..240
      *(uint4*)&Hs[row * 256 + (cb ^ SWZ(row))] = w;
    }
  }
  __syncthreads();

  floatx4 acc[2][4];   // [jt][tt]; hidden rows (2*wave+jt)*16+q*4+r, tok tt*16+l15

  // ---- layer 1: K = 128 bf16, A = W1^T, B = x; acc init = bias ----
#pragma unroll
  for (int jt = 0; jt < 2; ++jt) {
    const float4 bb = *(const float4*)&b1[(wave * 2 + jt) * 16 + q * 4];
#pragma unroll
    for (int tt = 0; tt < 4; ++tt)
      acc[jt][tt] = (floatx4){bb.x, bb.y, bb.z, bb.w};
  }
#pragma unroll
  for (int kc = 0; kc < 4; ++kc) {
    bf16x8 a0 = *(const bf16x8*)(pW1 + ((((wave * 2 + 0) * 4 + kc) * 64 + lane) << 3));
    bf16x8 a1 = *(const bf16x8*)(pW1 + ((((wave * 2 + 1) * 4 + kc) * 64 + lane) << 3));
#pragma unroll
    for (int tt = 0; tt < 4; ++tt) {
      const int t = tt * 16 + l15;
      bf16x8 b = *(const bf16x8*)&Hs[t * 256 + ((kc * 64 + q * 16) ^ SWZ(t))];
      acc[0][tt] = __builtin_amdgcn_mfma_f32_16x16x32_bf16(a0, b, acc[0][tt], 0, 0, 0);
      acc[1][tt] = __builtin_amdgcn_mfma_f32_16x16x32_bf16(a1, b, acc[1][tt], 0, 0, 0);
    }
  }
  __syncthreads();   // x reads done before h1 overwrites

  // ---- h1 = relu(acc) -> fp8, row stride 256B (overwrites x region) ----
#pragma unroll
  for (int jt = 0; jt < 2; ++jt) {
    const int j0 = (wave * 2 + jt) * 16 + q * 4;   // byte col == hidden idx
#pragma unroll
    for (int tt = 0; tt < 4; ++tt) {
      const int t = tt * 16 + l15;
      float v0 = fmaxf(acc[jt][tt][0], 0.f);
      float v1 = fmaxf(acc[jt][tt][1], 0.f);
      float v2 = fmaxf(acc[jt][tt][2], 0.f);
      float v3 = fmaxf(acc[jt][tt][3], 0.f);
      int u = __builtin_amdgcn_cvt_pk_fp8_f32(v0, v1, 0, false);
      u = __builtin_amdgcn_cvt_pk_fp8_f32(v2, v3, u, true);
      *(uint32_t*)&Hs[t * 256 + (j0 ^ SWZ(t))] = (uint32_t)u;
    }
  }
  __syncthreads();

  // ---- layer 2: K = 256 fp8, A = W2^T, B = h1 ----
#pragma unroll
  for (int jt = 0; jt < 2; ++jt) {
    const float4 bb = *(const float4*)&b2[(wave * 2 + jt) * 16 + q * 4];
#pragma unroll
    for (int tt = 0; tt < 4; ++tt)
      acc[jt][tt] = (floatx4){bb.x, bb.y, bb.z, bb.w};
  }
#pragma unroll
  for (int kc = 0; kc < 8; ++kc) {
    long a0 = *(const long*)(pW2 + ((((wave * 2 + 0) * 8 + kc) * 64 + lane) << 3));
    long a1 = *(const long*)(pW2 + ((((wave * 2 + 1) * 8 + kc) * 64 + lane) << 3));
#pragma unroll
    for (int tt = 0; tt < 4; ++tt) {
      const int t = tt * 16 + l15;
      long b = *(const long*)&Hs[t * 256 + ((kc * 32 + q * 8) ^ SWZ(t))];
      acc[0][tt] = __builtin_amdgcn_mfma_f32_16x16x32_fp8_fp8(a0, b, acc[0][tt], 0, 0, 0);
      acc[1][tt] = __builtin_amdgcn_mfma_f32_16x16x32_fp8_fp8(a1, b, acc[1][tt], 0, 0, 0);
    }
  }
  __syncthreads();   // h1 reads done before h2 overwrites

  // ---- h2 = relu(acc) -> fp8 ----
#pragma unroll
  for (int jt = 0; jt < 2; ++jt) {
    const int j0 = (wave * 2 + jt) * 16 + q * 4;
#pragma unroll
    for (int tt = 0; tt < 4; ++tt) {
      const int t = tt * 16 + l15;
      float v0 = fmaxf(acc[jt][tt][0], 0.f);
      float v1 = fmaxf(acc[jt][tt][1], 0.f);
      float v2 = fmaxf(acc[jt][tt][2], 0.f);
      float v3 = fmaxf(acc[jt][tt][3], 0.f);
      int u = __builtin_amdgcn_cvt_pk_fp8_f32(v0, v1, 0, false);
      u = __builtin_amdgcn_cvt_pk_fp8_f32(v2, v3, u, true);
      *(uint32_t*)&Hs[t * 256 + (j0 ^ SWZ(t))] = (uint32_t)u;
    }
  }
  __syncthreads();

  // ---- layer 3: K = 256 fp8, A = W3^T, B = h2, fused token-sum ----
#pragma unroll
  for (int jt = 0; jt < 2; ++jt) {
    const float4 bb = *(const float4*)&b3[(wave * 2 + jt) * 16 + q * 4];
#pragma unroll
    for (int tt = 0; tt < 4; ++tt)
      acc[jt][tt] = (floatx4){bb.x, bb.y, bb.z, bb.w};
  }
#pragma unroll
  for (int kc = 0; kc < 8; ++kc) {
    long a0 = *(const long*)(pW3 + ((((wave * 2 + 0) * 8 + kc) * 64 + lane) << 3));
    long a1 = *(const long*)(pW3 + ((((wave * 2 + 1) * 8 + kc) * 64 + lane) << 3));
#pragma unroll
    for (int tt = 0; tt < 4; ++tt) {
      const int t = tt * 16 + l15;
      long b = *(const long*)&Hs[t * 256 + ((kc * 32 + q * 8) ^ SWZ(t))];
      acc[0][tt] = __builtin_amdgcn_mfma_f32_16x16x32_fp8_fp8(a0, b, acc[0][tt], 0, 0, 0);
      acc[1][tt] = __builtin_amdgcn_mfma_f32_16x16x32_fp8_fp8(a1, b, acc[1][tt], 0, 0, 0);
    }
  }

  // relu + token-sum: serial over tt, shfl_xor butterfly over l15 (16 lanes),
  // then coalesced via 1KB scratch (separate region -> single barrier).
#pragma unroll
  for (int jt = 0; jt < 2; ++jt) {
    float s0 = 0.f, s1 = 0.f, s2 = 0.f, s3 = 0.f;
#pragma unroll
    for (int tt = 0; tt < 4; ++tt) {
      s0 += fmaxf(acc[jt][tt][0], 0.f);
      s1 += fmaxf(acc[jt][tt][1], 0.f);
      s2 += fmaxf(acc[jt][tt][2], 0.f);
      s3 += fmaxf(acc[jt][tt][3], 0.f);
    }
#pragma unroll
    for (int m = 1; m <= 8; m <<= 1) {
      s0 += __shfl_xor(s0, m);
      s1 += __shfl_xor(s1, m);
      s2 += __shfl_xor(s2, m);
      s3 += __shfl_xor(s3, m);
    }
    if (l15 == 0)   // lanes q=0..3: rows (2*wave+jt)*16 + q*4 + {0..3}
      *(float4*)&scr[(wave * 2 + jt) * 16 + q * 4] = (float4){s0, s1, s2, s3};
  }
  __syncthreads();
  if (tid < NHID)
    atomicAdd(&msum[batch * NHID + tid], scr[tid]);
}

// ---------------------------------------------------------------------------
// Decoder: 128 blocks = (batch x d2-quarter), 1024 threads. Each block
// computes the full d1 (redundant x4, D1 is L2-resident), its 128-wide d2
// quarter, and atomicAdds its partial L3 dot into out (pre-init'd to c3).
// ---------------------------------------------------------------------------
__global__ __launch_bounds__(1024) void decoder(
    const float* __restrict__ msum,
    const float* __restrict__ D1, const float* __restrict__ c1,
    const float* __restrict__ D2, const float* __restrict__ c2,
    const float* __restrict__ D3,
    float* __restrict__ out) {
  __shared__ float p[NHID];
  __shared__ float d1[NDEC];
  __shared__ float d2q[128];
  __shared__ __align__(16) float red[4096];   // 16 KB
  const int b = blockIdx.x >> 2, qd = blockIdx.x & 3, t = threadIdx.x;

  if (t < NHID) {
    float m = msum[b * NHID + t] * (1.f / NTOK);
    p[t] = m * m;                        // relu(m^2) == m^2
  }
  __syncthreads();

  // ---- layer 1 (full, redundant x4): K = 256 -> 32 k per split ----
  {
    const int jg = t & 127;              // j-group of 4
    const int ks = t >> 7;               // 0..7 K-split
    const float4* D1v = (const float4*)D1;   // [256][128] float4
    float4 s = {0.f, 0.f, 0.f, 0.f};
    for (int k = ks * 32; k < ks * 32 + 32; ++k) {
      float4 w = D1v[k * 128 + jg];
      float pv = p[k];
      s.x += pv * w.x; s.y += pv * w.y; s.z += pv * w.z; s.w += pv * w.w;
    }
    *(float4*)&red[t * 4] = s;
    __syncthreads();
    if (t < NDEC) {
      float v = c1[t];
#pragma unroll
      for (int i = 0; i < 8; ++i) v += red[i * 512 + t];
      d1[t] = fmaxf(v, 0.f);
    }
    __syncthreads();
  }

  // ---- layer 2 (quarter): 128 outs, K = 512 -> 32 splits x 16 k ----
  {
    const int jg2 = t & 31;              // float4 group within quarter
    const int ks2 = t >> 5;              // 0..31 K-split
    const float4* D2v = (const float4*)D2;   // [512][128] float4
    float4 s = {0.f, 0.f, 0.f, 0.f};
    for (int k = ks2 * 16; k < ks2 * 16 + 16; ++k) {
      float4 w = D2v[k * 128 + qd * 32 + jg2];
      float hv = d1[k];
      s.x += hv * w.x; s.y += hv * w.y; s.z += hv * w.z; s.w += hv * w.w;
    }
    *(float4*)&red[t * 4] = s;           // == red[ks2*128 + jg2*4 + c]
    __syncthreads();
    if (t < 128) {
      float v = c2[qd * 128 + t];
#pragma unroll
      for (int i = 0; i < 32; ++i) v += red[i * 128 + t];
      d2q[t] = fmaxf(v, 0.f);
    }
    __syncthreads();
  }

  // ---- layer 3 partial: quarter K = 128; 64 k-chunks x 16 j-slots ----
  {
    const int j3 = t & 15;
    const int kc = t >> 4;               // 0..63, 2 k's each
    float s = 0.f;
    if (j3 < NOUTC)
      for (int k = kc * 2; k < kc * 2 + 2; ++k)
        s += d2q[k] * D3[(qd * 128 + k) * NOUTC + j3];
    red[t] = s;
    __syncthreads();
    if (t < NOUTC) {
      float v = 0.f;
#pragma unroll
      for (int i = 0; i < 64; ++i) v += red[i * 16 + t];
      atomicAdd(&out[b * NOUTC + t], v);
    }
  }
}

// ---------------------------------------------------------------------------
extern "C" void kernel_launch(void* const* d_in, const int* in_sizes, int n_in,
                              void* d_out, int out_size, void* d_ws, size_t ws_size,
                              hipStream_t stream) {
  const float* x  = (const float*)d_in[0];
  const float* W1 = (const float*)d_in[1];
  const float* b1 = (const float*)d_in[2];
  const float* W2 = (const float*)d_in[3];
  const float* b2 = (const float*)d_in[4];
  const float* W3 = (const float*)d_in[5];
  const float* b3 = (const float*)d_in[6];
  const float* D1 = (const float*)d_in[7];
  const float* c1 = (const float*)d_in[8];
  const float* D2 = (const float*)d_in[9];
  const float* c2 = (const float*)d_in[10];
  const float* D3 = (const float*)d_in[11];
  const float* c3 = (const float*)d_in[12];

  // ws: [0,64K) bf16 W1 | [64K,128K) fp8 W2 | [128K,192K) fp8 W3 |
  //     [384K,416K) msum
  uint8_t* pW   = (uint8_t*)d_ws;
  float*   msum = (float*)((char*)d_ws + 384 * 1024);

  pack_weights<<<640, 256, 0, stream>>>(W1, W2, W3, c3, pW, msum,
                                        (float*)d_out);
  encoder<<<NBLK, 512, 0, stream>>>(x, pW, b1, b2, b3, msum);
  decoder<<<128, 1024, 0, stream>>>(msum, D1, c1, D2, c2, D3,
                                    (float*)d_out);
}

// Round 8
// 157.866 us; speedup vs baseline: 1.1227x; 1.1227x over previous
//
#include <hip/hip_runtime.h>
#include <hip/hip_bf16.h>
#include <stdint.h>

// ---------------------------------------------------------------------------
// TensorNet: fused encoder MLP (128->256->256->256, relu) over 32x4096 tokens,
// per-batch mean -> p = relu(m^2) -> decoder MLP (256->512->512->10).
//
// R23: R22 minus the min-waves launch bound. R22 proved the 512-thread/8-wave
// shape reaches 65% occupancy (wave-slot model confirmed) but
// __launch_bounds__(512,8) made the compiler allocate VGPR=32 < live-set ->
// 160MB spill traffic = the whole 65us. This round: plain
// __launch_bounds__(512); live-set ~52-58 (acc[2][4]=32 + frags + addr)
// should float to VGPR<=64 -> natural 8 waves/SIMD cap, no spills.
// Wave owns 32 hidden x 64 tokens; fp8 e4m3 layers 2/3 (layout verified
// R21/R22, absmax unchanged); coalesced epilogue atomics via 1KB scratch.
//
// HARD RULES from the log:
//  - NEVER pass a min-waves arg to __launch_bounds__ (R5, R19, R22:
//    compiler under-allocates vs its own budget and spills catastrophically).
//  - NEVER grow per-wave a-load count for "sharing" (R18: 185us).
//  - NEVER shrink MTILE / grow block count (R20: +34% blocks, no gain).
// Rejected: MTILE=128 (R16), MTILE=48 (R20), wave->token remap (R18),
// direct-global B-frags (R5/R6), ping-pong (R13), cooperative (R11),
// decoder-in-encoder (R14/R15).
// Fallback if this round is neutral/negative: revert to R17 (best: 159.6us
// total, encoder 55.8us) as the final configuration.
// ---------------------------------------------------------------------------

#define NIN   128
#define NHID  256
#define NDEC  512
#define NOUTC 10
#define BATCH 32
#define NTOK  4096
#define MTILE 64
#define NBLK  (BATCH * (NTOK / MTILE))   // 2048 encoder tiles

#define SWZ(t) (((t) & 7) << 4)          // XOR swizzle, byte bits 4-6

typedef short bf16x8 __attribute__((ext_vector_type(8)));
typedef float floatx4 __attribute__((ext_vector_type(4)));

__device__ __forceinline__ uint16_t f2b(float f) {
  union { uint32_t u; float f; } v; v.f = f;
  uint32_t r = v.u + 0x7FFFu + ((v.u >> 16) & 1u);   // RNE
  return (uint16_t)(r >> 16);
}
__device__ __forceinline__ uint32_t pkbf(float lo, float hi) {
  __hip_bfloat162 h = __float22bfloat162_rn(float2{lo, hi});  // v_cvt_pk_bf16_f32
  union { __hip_bfloat162 h; uint32_t u; } c; c.h = h;
  return c.u;
}

// ---------------------------------------------------------------------------
// Pack weights into MFMA-A-fragment order: W1 -> bf16 (bytes [0,64K)),
// W2/W3 -> fp8 e4m3 ([64K,128K) / [128K,192K)). Also zero-inits msum and
// pre-loads out with c3 (decoder atomics accumulate; stream-ordered).
// ---------------------------------------------------------------------------
__global__ __launch_bounds__(256) void pack_weights(
    const float* __restrict__ W1, const float* __restrict__ W2,
    const float* __restrict__ W3, const float* __restrict__ c3,
    uint8_t* __restrict__ pW, float* __restrict__ msum,
    float* __restrict__ out) {
  int p = blockIdx.x * blockDim.x + threadIdx.x;
  if (p < BATCH * NHID) msum[p] = 0.f;
  if (p < BATCH * NOUTC) out[p] = c3[p % NOUTC];
  if (p < 32768) {
    // W1: K=128, KC=4, bf16
    int j = p & 7, ln = (p >> 3) & 63, rest = p >> 9;
    int kc = rest & 3, mt = rest >> 2;
    int m = mt * 16 + (ln & 15);
    int k = kc * 32 + ((ln >> 4) << 3) + j;
    ((uint16_t*)pW)[p] = f2b(W1[k * NHID + m]);
  } else {
    int p2 = p - 32768;
    const float* W = (p2 < 65536) ? W2 : W3;
    int base = (p2 < 65536) ? 65536 : 131072;
    if (p2 >= 65536) p2 -= 65536;
    // K=256, KC=8, fp8 e4m3
    int j = p2 & 7, ln = (p2 >> 3) & 63, rest = p2 >> 9;
    int kc = rest & 7, mt = rest >> 3;
    int m = mt * 16 + (ln & 15);
    int k = kc * 32 + ((ln >> 4) << 3) + j;
    int r = __builtin_amdgcn_cvt_pk_fp8_f32(W[k * NHID + m], 0.f, 0, false);
    pW[base + p2] = (uint8_t)(r & 0xFF);
  }
}

// ---------------------------------------------------------------------------
// Fused encoder. Block = 512 thr (8 waves), 64 tokens. Wave w owns hidden
// rows [32w,32w+32) (jt=0..1); acc[2][4] = 32 VGPRs. LDS: 16KB tile + 1KB
// scratch. VGPR free-floats (live-set ~55) -> expect <=64 -> 8 waves/SIMD.
// ---------------------------------------------------------------------------
__global__ __launch_bounds__(512) void encoder(
    const float* __restrict__ x,        // [BATCH*NTOK][NIN] fp32
    const uint8_t* __restrict__ pW,
    const float* __restrict__ b1,
    const float* __restrict__ b2,
    const float* __restrict__ b3,
    float* __restrict__ msum) {         // [BATCH][NHID] fp32 accum
  __shared__ __align__(16) uint8_t Hs[MTILE * 256];   // 16384 B
  __shared__ __align__(16) float scr[NHID];           // 1024 B

  const int tid  = threadIdx.x;
  const int wave = tid >> 6;
  const int lane = tid & 63;
  const int l15  = lane & 15;
  const int q    = lane >> 4;
  const int tok0  = blockIdx.x * MTILE;
  const int batch = blockIdx.x >> 6;          // 64 tiles per batch

  const uint16_t* pW1 = (const uint16_t*)pW;  // bf16 frags, KC=4
  const uint8_t*  pW2 = pW + 65536;           // fp8 frags, KC=8
  const uint8_t*  pW3 = pW + 131072;          // fp8 frags, KC=8

  // ---- stage x tile: 64 tokens x 128 ch fp32 -> bf16, row stride 256B ----
  {
    const float4* xv = (const float4*)(x + (size_t)tok0 * NIN);
#pragma unroll
    for (int i = 0; i < 2; ++i) {
      const int u = tid + i * 512;            // 8-float unit, 0..1023
      float4 va = xv[2 * u];
      float4 vb = xv[2 * u + 1];
      uint4 w = make_uint4(pkbf(va.x, va.y), pkbf(va.z, va.w),
                           pkbf(vb.x, vb.y), pkbf(vb.z, vb.w));
      const int row = u >> 4;                 // token 0..63
      const int cb  = (u & 15) << 4;          // byte col 0..240
      *(uint4*)&Hs[row * 256 + (cb ^ SWZ(row))] = w;
    }
  }
  __syncthreads();

  floatx4 acc[2][4];   // [jt][tt]; hidden rows (2*wave+jt)*16+q*4+r, tok tt*16+l15

  // ---- layer 1: K = 128 bf16, A = W1^T, B = x; acc init = bias ----
#pragma unroll
  for (int jt = 0; jt < 2; ++jt) {
    const float4 bb = *(const float4*)&b1[(wave * 2 + jt) * 16 + q * 4];
#pragma unroll
    for (int tt = 0; tt < 4; ++tt)
      acc[jt][tt] = (floatx4){bb.x, bb.y, bb.z, bb.w};
  }
#pragma unroll
  for (int kc = 0; kc < 4; ++kc) {
    bf16x8 a0 = *(const bf16x8*)(pW1 + ((((wave * 2 + 0) * 4 + kc) * 64 + lane) << 3));
    bf16x8 a1 = *(const bf16x8*)(pW1 + ((((wave * 2 + 1) * 4 + kc) * 64 + lane) << 3));
#pragma unroll
    for (int tt = 0; tt < 4; ++tt) {
      const int t = tt * 16 + l15;
      bf16x8 b = *(const bf16x8*)&Hs[t * 256 + ((kc * 64 + q * 16) ^ SWZ(t))];
      acc[0][tt] = __builtin_amdgcn_mfma_f32_16x16x32_bf16(a0, b, acc[0][tt], 0, 0, 0);
      acc[1][tt] = __builtin_amdgcn_mfma_f32_16x16x32_bf16(a1, b, acc[1][tt], 0, 0, 0);
    }
  }
  __syncthreads();   // x reads done before h1 overwrites

  // ---- h1 = relu(acc) -> fp8, row stride 256B (overwrites x region) ----
#pragma unroll
  for (int jt = 0; jt < 2; ++jt) {
    const int j0 = (wave * 2 + jt) * 16 + q * 4;   // byte col == hidden idx
#pragma unroll
    for (int tt = 0; tt < 4; ++tt) {
      const int t = tt * 16 + l15;
      float v0 = fmaxf(acc[jt][tt][0], 0.f);
      float v1 = fmaxf(acc[jt][tt][1], 0.f);
      float v2 = fmaxf(acc[jt][tt][2], 0.f);
      float v3 = fmaxf(acc[jt][tt][3], 0.f);
      int u = __builtin_amdgcn_cvt_pk_fp8_f32(v0, v1, 0, false);
      u = __builtin_amdgcn_cvt_pk_fp8_f32(v2, v3, u, true);
      *(uint32_t*)&Hs[t * 256 + (j0 ^ SWZ(t))] = (uint32_t)u;
    }
  }
  __syncthreads();

  // ---- layer 2: K = 256 fp8, A = W2^T, B = h1 ----
#pragma unroll
  for (int jt = 0; jt < 2; ++jt) {
    const float4 bb = *(const float4*)&b2[(wave * 2 + jt) * 16 + q * 4];
#pragma unroll
    for (int tt = 0; tt < 4; ++tt)
      acc[jt][tt] = (floatx4){bb.x, bb.y, bb.z, bb.w};
  }
#pragma unroll
  for (int kc = 0; kc < 8; ++kc) {
    long a0 = *(const long*)(pW2 + ((((wave * 2 + 0) * 8 + kc) * 64 + lane) << 3));
    long a1 = *(const long*)(pW2 + ((((wave * 2 + 1) * 8 + kc) * 64 + lane) << 3));
#pragma unroll
    for (int tt = 0; tt < 4; ++tt) {
      const int t = tt * 16 + l15;
      long b = *(const long*)&Hs[t * 256 + ((kc * 32 + q * 8) ^ SWZ(t))];
      acc[0][tt] = __builtin_amdgcn_mfma_f32_16x16x32_fp8_fp8(a0, b, acc[0][tt], 0, 0, 0);
      acc[1][tt] = __builtin_amdgcn_mfma_f32_16x16x32_fp8_fp8(a1, b, acc[1][tt], 0, 0, 0);
    }
  }
  __syncthreads();   // h1 reads done before h2 overwrites

  // ---- h2 = relu(acc) -> fp8 ----
#pragma unroll
  for (int jt = 0; jt < 2; ++jt) {
    const int j0 = (wave * 2 + jt) * 16 + q * 4;
#pragma unroll
    for (int tt = 0; tt < 4; ++tt) {
      const int t = tt * 16 + l15;
      float v0 = fmaxf(acc[jt][tt][0], 0.f);
      float v1 = fmaxf(acc[jt][tt][1], 0.f);
      float v2 = fmaxf(acc[jt][tt][2], 0.f);
      float v3 = fmaxf(acc[jt][tt][3], 0.f);
      int u = __builtin_amdgcn_cvt_pk_fp8_f32(v0, v1, 0, false);
      u = __builtin_amdgcn_cvt_pk_fp8_f32(v2, v3, u, true);
      *(uint32_t*)&Hs[t * 256 + (j0 ^ SWZ(t))] = (uint32_t)u;
    }
  }
  __syncthreads();

  // ---- layer 3: K = 256 fp8, A = W3^T, B = h2, fused token-sum ----
#pragma unroll
  for (int jt = 0; jt < 2; ++jt) {
    const float4 bb = *(const float4*)&b3[(wave * 2 + jt) * 16 + q * 4];
#pragma unroll
    for (int tt = 0; tt < 4; ++tt)
      acc[jt][tt] = (floatx4){bb.x, bb.y, bb.z, bb.w};
  }
#pragma unroll
  for (int kc = 0; kc < 8; ++kc) {
    long a0 = *(const long*)(pW3 + ((((wave * 2 + 0) * 8 + kc) * 64 + lane) << 3));
    long a1 = *(const long*)(pW3 + ((((wave * 2 + 1) * 8 + kc) * 64 + lane) << 3));
#pragma unroll
    for (int tt = 0; tt < 4; ++tt) {
      const int t = tt * 16 + l15;
      long b = *(const long*)&Hs[t * 256 + ((kc * 32 + q * 8) ^ SWZ(t))];
      acc[0][tt] = __builtin_amdgcn_mfma_f32_16x16x32_fp8_fp8(a0, b, acc[0][tt], 0, 0, 0);
      acc[1][tt] = __builtin_amdgcn_mfma_f32_16x16x32_fp8_fp8(a1, b, acc[1][tt], 0, 0, 0);
    }
  }

  // relu + token-sum: serial over tt, shfl_xor butterfly over l15 (16 lanes),
  // then coalesced via 1KB scratch (separate region -> single barrier).
#pragma unroll
  for (int jt = 0; jt < 2; ++jt) {
    float s0 = 0.f, s1 = 0.f, s2 = 0.f, s3 = 0.f;
#pragma unroll
    for (int tt = 0; tt < 4; ++tt) {
      s0 += fmaxf(acc[jt][tt][0], 0.f);
      s1 += fmaxf(acc[jt][tt][1], 0.f);
      s2 += fmaxf(acc[jt][tt][2], 0.f);
      s3 += fmaxf(acc[jt][tt][3], 0.f);
    }
#pragma unroll
    for (int m = 1; m <= 8; m <<= 1) {
      s0 += __shfl_xor(s0, m);
      s1 += __shfl_xor(s1, m);
      s2 += __shfl_xor(s2, m);
      s3 += __shfl_xor(s3, m);
    }
    if (l15 == 0)   // lanes q=0..3: rows (2*wave+jt)*16 + q*4 + {0..3}
      *(float4*)&scr[(wave * 2 + jt) * 16 + q * 4] = (float4){s0, s1, s2, s3};
  }
  __syncthreads();
  if (tid < NHID)
    atomicAdd(&msum[batch * NHID + tid], scr[tid]);
}

// ---------------------------------------------------------------------------
// Decoder: 128 blocks = (batch x d2-quarter), 1024 threads. Each block
// computes the full d1 (redundant x4, D1 is L2-resident), its 128-wide d2
// quarter, and atomicAdds its partial L3 dot into out (pre-init'd to c3).
// ---------------------------------------------------------------------------
__global__ __launch_bounds__(1024) void decoder(
    const float* __restrict__ msum,
    const float* __restrict__ D1, const float* __restrict__ c1,
    const float* __restrict__ D2, const float* __restrict__ c2,
    const float* __restrict__ D3,
    float* __restrict__ out) {
  __shared__ float p[NHID];
  __shared__ float d1[NDEC];
  __shared__ float d2q[128];
  __shared__ __align__(16) float red[4096];   // 16 KB
  const int b = blockIdx.x >> 2, qd = blockIdx.x & 3, t = threadIdx.x;

  if (t < NHID) {
    float m = msum[b * NHID + t] * (1.f / NTOK);
    p[t] = m * m;                        // relu(m^2) == m^2
  }
  __syncthreads();

  // ---- layer 1 (full, redundant x4): K = 256 -> 32 k per split ----
  {
    const int jg = t & 127;              // j-group of 4
    const int ks = t >> 7;               // 0..7 K-split
    const float4* D1v = (const float4*)D1;   // [256][128] float4
    float4 s = {0.f, 0.f, 0.f, 0.f};
    for (int k = ks * 32; k < ks * 32 + 32; ++k) {
      float4 w = D1v[k * 128 + jg];
      float pv = p[k];
      s.x += pv * w.x; s.y += pv * w.y; s.z += pv * w.z; s.w += pv * w.w;
    }
    *(float4*)&red[t * 4] = s;
    __syncthreads();
    if (t < NDEC) {
      float v = c1[t];
#pragma unroll
      for (int i = 0; i < 8; ++i) v += red[i * 512 + t];
      d1[t] = fmaxf(v, 0.f);
    }
    __syncthreads();
  }

  // ---- layer 2 (quarter): 128 outs, K = 512 -> 32 splits x 16 k ----
  {
    const int jg2 = t & 31;              // float4 group within quarter
    const int ks2 = t >> 5;              // 0..31 K-split
    const float4* D2v = (const float4*)D2;   // [512][128] float4
    float4 s = {0.f, 0.f, 0.f, 0.f};
    for (int k = ks2 * 16; k < ks2 * 16 + 16; ++k) {
      float4 w = D2v[k * 128 + qd * 32 + jg2];
      float hv = d1[k];
      s.x += hv * w.x; s.y += hv * w.y; s.z += hv * w.z; s.w += hv * w.w;
    }
    *(float4*)&red[t * 4] = s;           // == red[ks2*128 + jg2*4 + c]
    __syncthreads();
    if (t < 128) {
      float v = c2[qd * 128 + t];
#pragma unroll
      for (int i = 0; i < 32; ++i) v += red[i * 128 + t];
      d2q[t] = fmaxf(v, 0.f);
    }
    __syncthreads();
  }

  // ---- layer 3 partial: quarter K = 128; 64 k-chunks x 16 j-slots ----
  {
    const int j3 = t & 15;
    const int kc = t >> 4;               // 0..63, 2 k's each
    float s = 0.f;
    if (j3 < NOUTC)
      for (int k = kc * 2; k < kc * 2 + 2; ++k)
        s += d2q[k] * D3[(qd * 128 + k) * NOUTC + j3];
    red[t] = s;
    __syncthreads();
    if (t < NOUTC) {
      float v = 0.f;
#pragma unroll
      for (int i = 0; i < 64; ++i) v += red[i * 16 + t];
      atomicAdd(&out[b * NOUTC + t], v);
    }
  }
}

// ---------------------------------------------------------------------------
extern "C" void kernel_launch(void* const* d_in, const int* in_sizes, int n_in,
                              void* d_out, int out_size, void* d_ws, size_t ws_size,
                              hipStream_t stream) {
  const float* x  = (const float*)d_in[0];
  const float* W1 = (const float*)d_in[1];
  const float* b1 = (const float*)d_in[2];
  const float* W2 = (const float*)d_in[3];
  const float* b2 = (const float*)d_in[4];
  const float* W3 = (const float*)d_in[5];
  const float* b3 = (const float*)d_in[6];
  const float* D1 = (const float*)d_in[7];
  const float* c1 = (const float*)d_in[8];
  const float* D2 = (const float*)d_in[9];
  const float* c2 = (const float*)d_in[10];
  const float* D3 = (const float*)d_in[11];
  const float* c3 = (const float*)d_in[12];

  // ws: [0,64K) bf16 W1 | [64K,128K) fp8 W2 | [128K,192K) fp8 W3 |
  //     [384K,416K) msum
  uint8_t* pW   = (uint8_t*)d_ws;
  float*   msum = (float*)((char*)d_ws + 384 * 1024);

  pack_weights<<<640, 256, 0, stream>>>(W1, W2, W3, c3, pW, msum,
                                        (float*)d_out);
  encoder<<<NBLK, 512, 0, stream>>>(x, pW, b1, b2, b3, msum);
  decoder<<<128, 1024, 0, stream>>>(msum, D1, c1, D2, c2, D3,
                                    (float*)d_out);
}

// Round 9
// 155.121 us; speedup vs baseline: 1.1426x; 1.0177x over previous
//
#include <hip/hip_runtime.h>
#include <hip/hip_bf16.h>
#include <stdint.h>

// ---------------------------------------------------------------------------
// TensorNet: fused encoder MLP (128->256->256->256, relu) over 32x4096 tokens,
// per-batch mean -> p = relu(m^2) -> decoder MLP (256->512->512->10).
//
// R24: attack the per-CU LDS pipe + barrier drains (R23 showed occupancy is
// NOT binding: +39% waves -> -0.7% time; ~8K LDS-pipe cyc/block x 8
// blocks/CU ~= 27us serialized is the structural term).
//  - fragment-major fp8 h layout: elem (t,k) at byte perm(k) =
//    ((k>>3)&3)*64 + (k>>5)*8 + (k&7); one ds_read_b128 = TWO kc fragments
//    -> fp8 b-reads halve (512->256/block).
//  - full-row swizzle SW2(t)=(t&15)<<4 (16 slots): makes L1/L2/L3 b-reads
//    bank-minimal (vs t&7's 2-way row aliasing = the 5.77M conflicts).
//  - h1 double-buffer (16KB buf1): L1 reads x(buf0) + writes h1(buf1) with
//    no barrier between; h2 reuses buf0. 6 barriers -> 4.
// Block = 512 thr (8 waves), wave owns 32 hidden; acc[2][4]=32 VGPR;
// fp8 e4m3 layers 2/3 (verified R21/R23); plain __launch_bounds__(512).
//
// HARD RULES from the log:
//  - NEVER pass a min-waves arg to __launch_bounds__ (R5, R19, R22: spills).
//  - NEVER grow per-wave a-load count for "sharing" (R18: 185us).
//  - NEVER shrink MTILE / grow block count (R20).
// Rejected: MTILE=128 (R16), MTILE=48 (R20), wave->token remap (R18),
// direct-global B-frags (R5/R6), ping-pong (R13), cooperative (R11),
// decoder-in-encoder (R14/R15).
// ---------------------------------------------------------------------------

#define NIN   128
#define NHID  256
#define NDEC  512
#define NOUTC 10
#define BATCH 32
#define NTOK  4096
#define MTILE 64
#define NBLK  (BATCH * (NTOK / MTILE))   // 2048 encoder tiles

#define SW2(t) (((t) & 15) << 4)         // XOR swizzle, byte bits 4-7

typedef short bf16x8 __attribute__((ext_vector_type(8)));
typedef float floatx4 __attribute__((ext_vector_type(4)));
typedef long  longx2  __attribute__((ext_vector_type(2)));

__device__ __forceinline__ uint16_t f2b(float f) {
  union { uint32_t u; float f; } v; v.f = f;
  uint32_t r = v.u + 0x7FFFu + ((v.u >> 16) & 1u);   // RNE
  return (uint16_t)(r >> 16);
}
__device__ __forceinline__ uint32_t pkbf(float lo, float hi) {
  __hip_bfloat162 h = __float22bfloat162_rn(float2{lo, hi});  // v_cvt_pk_bf16_f32
  union { __hip_bfloat162 h; uint32_t u; } c; c.h = h;
  return c.u;
}

// ---------------------------------------------------------------------------
// Pack weights into MFMA-A-fragment order: W1 -> bf16 (bytes [0,64K)),
// W2/W3 -> fp8 e4m3 ([64K,128K) / [128K,192K)). Also zero-inits msum and
// pre-loads out with c3 (decoder atomics accumulate; stream-ordered).
// ---------------------------------------------------------------------------
__global__ __launch_bounds__(256) void pack_weights(
    const float* __restrict__ W1, const float* __restrict__ W2,
    const float* __restrict__ W3, const float* __restrict__ c3,
    uint8_t* __restrict__ pW, float* __restrict__ msum,
    float* __restrict__ out) {
  int p = blockIdx.x * blockDim.x + threadIdx.x;
  if (p < BATCH * NHID) msum[p] = 0.f;
  if (p < BATCH * NOUTC) out[p] = c3[p % NOUTC];
  if (p < 32768) {
    // W1: K=128, KC=4, bf16
    int j = p & 7, ln = (p >> 3) & 63, rest = p >> 9;
    int kc = rest & 3, mt = rest >> 2;
    int m = mt * 16 + (ln & 15);
    int k = kc * 32 + ((ln >> 4) << 3) + j;
    ((uint16_t*)pW)[p] = f2b(W1[k * NHID + m]);
  } else {
    int p2 = p - 32768;
    const float* W = (p2 < 65536) ? W2 : W3;
    int base = (p2 < 65536) ? 65536 : 131072;
    if (p2 >= 65536) p2 -= 65536;
    // K=256, KC=8, fp8 e4m3
    int j = p2 & 7, ln = (p2 >> 3) & 63, rest = p2 >> 9;
    int kc = rest & 7, mt = rest >> 3;
    int m = mt * 16 + (ln & 15);
    int k = kc * 32 + ((ln >> 4) << 3) + j;
    int r = __builtin_amdgcn_cvt_pk_fp8_f32(W[k * NHID + m], 0.f, 0, false);
    pW[base + p2] = (uint8_t)(r & 0xFF);
  }
}

// ---------------------------------------------------------------------------
// Fused encoder. Block = 512 thr (8 waves), 64 tokens. Wave w owns hidden
// rows [32w,32w+32). Hs0: x tile (bf16), later h2 (fp8 fragment-major);
// Hs1: h1 (fp8 fragment-major). 4 barriers total.
// ---------------------------------------------------------------------------
__global__ __launch_bounds__(512) void encoder(
    const float* __restrict__ x,        // [BATCH*NTOK][NIN] fp32
    const uint8_t* __restrict__ pW,
    const float* __restrict__ b1,
    const float* __restrict__ b2,
    const float* __restrict__ b3,
    float* __restrict__ msum) {         // [BATCH][NHID] fp32 accum
  __shared__ __align__(16) uint8_t Hs0[MTILE * 256];  // 16384 B: x, then h2
  __shared__ __align__(16) uint8_t Hs1[MTILE * 256];  // 16384 B: h1
  __shared__ __align__(16) float scr[NHID];           // 1024 B

  const int tid  = threadIdx.x;
  const int wave = tid >> 6;
  const int lane = tid & 63;
  const int l15  = lane & 15;
  const int q    = lane >> 4;
  const int tok0  = blockIdx.x * MTILE;
  const int batch = blockIdx.x >> 6;          // 64 tiles per batch

  const uint16_t* pW1 = (const uint16_t*)pW;  // bf16 frags, KC=4
  const uint8_t*  pW2 = pW + 65536;           // fp8 frags, KC=8
  const uint8_t*  pW3 = pW + 131072;          // fp8 frags, KC=8

  // ---- stage x tile: 64 tok x 128 ch fp32 -> bf16, row 256B, SW2 ----
  {
    const float4* xv = (const float4*)(x + (size_t)tok0 * NIN);
#pragma unroll
    for (int i = 0; i < 2; ++i) {
      const int u = tid + i * 512;            // 8-float unit, 0..1023
      float4 va = xv[2 * u];
      float4 vb = xv[2 * u + 1];
      uint4 w = make_uint4(pkbf(va.x, va.y), pkbf(va.z, va.w),
                           pkbf(vb.x, vb.y), pkbf(vb.z, vb.w));
      const int row = u >> 4;                 // token 0..63
      const int cb  = (u & 15) << 4;          // byte col 0..240
      *(uint4*)&Hs0[row * 256 + (cb ^ SW2(row))] = w;
    }
  }
  __syncthreads();   // (1) x staged

  floatx4 acc[2][4];   // [jt][tt]

  // ---- layer 1: K = 128 bf16, A = W1^T, B = x(Hs0); acc init = bias ----
#pragma unroll
  for (int jt = 0; jt < 2; ++jt) {
    const float4 bb = *(const float4*)&b1[(wave * 2 + jt) * 16 + q * 4];
#pragma unroll
    for (int tt = 0; tt < 4; ++tt)
      acc[jt][tt] = (floatx4){bb.x, bb.y, bb.z, bb.w};
  }
#pragma unroll
  for (int kc = 0; kc < 4; ++kc) {
    bf16x8 a0 = *(const bf16x8*)(pW1 + ((((wave * 2 + 0) * 4 + kc) * 64 + lane) << 3));
    bf16x8 a1 = *(const bf16x8*)(pW1 + ((((wave * 2 + 1) * 4 + kc) * 64 + lane) << 3));
#pragma unroll
    for (int tt = 0; tt < 4; ++tt) {
      const int t = tt * 16 + l15;
      bf16x8 b = *(const bf16x8*)&Hs0[t * 256 + ((kc * 64 + q * 16) ^ SW2(t))];
      acc[0][tt] = __builtin_amdgcn_mfma_f32_16x16x32_bf16(a0, b, acc[0][tt], 0, 0, 0);
      acc[1][tt] = __builtin_amdgcn_mfma_f32_16x16x32_bf16(a1, b, acc[1][tt], 0, 0, 0);
    }
  }
  // h1 -> Hs1 (fragment-major fp8); no barrier needed (different buffer)
#pragma unroll
  for (int jt = 0; jt < 2; ++jt) {
    const int j0 = (wave * 2 + jt) * 16 + q * 4;
    const int pb = ((j0 >> 3) & 3) * 64 + (j0 >> 5) * 8 + (j0 & 7);
#pragma unroll
    for (int tt = 0; tt < 4; ++tt) {
      const int t = tt * 16 + l15;
      float v0 = fmaxf(acc[jt][tt][0], 0.f);
      float v1 = fmaxf(acc[jt][tt][1], 0.f);
      float v2 = fmaxf(acc[jt][tt][2], 0.f);
      float v3 = fmaxf(acc[jt][tt][3], 0.f);
      int u = __builtin_amdgcn_cvt_pk_fp8_f32(v0, v1, 0, false);
      u = __builtin_amdgcn_cvt_pk_fp8_f32(v2, v3, u, true);
      *(uint32_t*)&Hs1[t * 256 + (pb ^ SW2(t))] = (uint32_t)u;
    }
  }
  __syncthreads();   // (2) h1 complete (implies all x reads done too)

  // ---- layer 2: K = 256 fp8, A = W2^T, B = h1(Hs1); h2 -> Hs0 ----
#pragma unroll
  for (int jt = 0; jt < 2; ++jt) {
    const float4 bb = *(const float4*)&b2[(wave * 2 + jt) * 16 + q * 4];
#pragma unroll
    for (int tt = 0; tt < 4; ++tt)
      acc[jt][tt] = (floatx4){bb.x, bb.y, bb.z, bb.w};
  }
#pragma unroll
  for (int kc2 = 0; kc2 < 4; ++kc2) {
    longx2 b[4];
#pragma unroll
    for (int tt = 0; tt < 4; ++tt) {
      const int t = tt * 16 + l15;
      b[tt] = *(const longx2*)&Hs1[t * 256 + ((q * 64 + kc2 * 16) ^ SW2(t))];
    }
#pragma unroll
    for (int s = 0; s < 2; ++s) {
      const int kc = kc2 * 2 + s;
      long a0 = *(const long*)(pW2 + ((((wave * 2 + 0) * 8 + kc) * 64 + lane) << 3));
      long a1 = *(const long*)(pW2 + ((((wave * 2 + 1) * 8 + kc) * 64 + lane) << 3));
#pragma unroll
      for (int tt = 0; tt < 4; ++tt) {
        acc[0][tt] = __builtin_amdgcn_mfma_f32_16x16x32_fp8_fp8(a0, b[tt][s], acc[0][tt], 0, 0, 0);
        acc[1][tt] = __builtin_amdgcn_mfma_f32_16x16x32_fp8_fp8(a1, b[tt][s], acc[1][tt], 0, 0, 0);
      }
    }
  }
  // h2 -> Hs0 (x is dead: barrier (2) proved all x reads finished)
#pragma unroll
  for (int jt = 0; jt < 2; ++jt) {
    const int j0 = (wave * 2 + jt) * 16 + q * 4;
    const int pb = ((j0 >> 3) & 3) * 64 + (j0 >> 5) * 8 + (j0 & 7);
#pragma unroll
    for (int tt = 0; tt < 4; ++tt) {
      const int t = tt * 16 + l15;
      float v0 = fmaxf(acc[jt][tt][0], 0.f);
      float v1 = fmaxf(acc[jt][tt][1], 0.f);
      float v2 = fmaxf(acc[jt][tt][2], 0.f);
      float v3 = fmaxf(acc[jt][tt][3], 0.f);
      int u = __builtin_amdgcn_cvt_pk_fp8_f32(v0, v1, 0, false);
      u = __builtin_amdgcn_cvt_pk_fp8_f32(v2, v3, u, true);
      *(uint32_t*)&Hs0[t * 256 + (pb ^ SW2(t))] = (uint32_t)u;
    }
  }
  __syncthreads();   // (3) h2 complete (implies all h1 reads done)

  // ---- layer 3: K = 256 fp8, A = W3^T, B = h2(Hs0), fused token-sum ----
#pragma unroll
  for (int jt = 0; jt < 2; ++jt) {
    const float4 bb = *(const float4*)&b3[(wave * 2 + jt) * 16 + q * 4];
#pragma unroll
    for (int tt = 0; tt < 4; ++tt)
      acc[jt][tt] = (floatx4){bb.x, bb.y, bb.z, bb.w};
  }
#pragma unroll
  for (int kc2 = 0; kc2 < 4; ++kc2) {
    longx2 b[4];
#pragma unroll
    for (int tt = 0; tt < 4; ++tt) {
      const int t = tt * 16 + l15;
      b[tt] = *(const longx2*)&Hs0[t * 256 + ((q * 64 + kc2 * 16) ^ SW2(t))];
    }
#pragma unroll
    for (int s = 0; s < 2; ++s) {
      const int kc = kc2 * 2 + s;
      long a0 = *(const long*)(pW3 + ((((wave * 2 + 0) * 8 + kc) * 64 + lane) << 3));
      long a1 = *(const long*)(pW3 + ((((wave * 2 + 1) * 8 + kc) * 64 + lane) << 3));
#pragma unroll
      for (int tt = 0; tt < 4; ++tt) {
        acc[0][tt] = __builtin_amdgcn_mfma_f32_16x16x32_fp8_fp8(a0, b[tt][s], acc[0][tt], 0, 0, 0);
        acc[1][tt] = __builtin_amdgcn_mfma_f32_16x16x32_fp8_fp8(a1, b[tt][s], acc[1][tt], 0, 0, 0);
      }
    }
  }

  // relu + token-sum: serial over tt, shfl_xor butterfly over l15 (16 lanes),
  // then coalesced via 1KB scratch (single extra barrier).
#pragma unroll
  for (int jt = 0; jt < 2; ++jt) {
    float s0 = 0.f, s1 = 0.f, s2 = 0.f, s3 = 0.f;
#pragma unroll
    for (int tt = 0; tt < 4; ++tt) {
      s0 += fmaxf(acc[jt][tt][0], 0.f);
      s1 += fmaxf(acc[jt][tt][1], 0.f);
      s2 += fmaxf(acc[jt][tt][2], 0.f);
      s3 += fmaxf(acc[jt][tt][3], 0.f);
    }
#pragma unroll
    for (int m = 1; m <= 8; m <<= 1) {
      s0 += __shfl_xor(s0, m);
      s1 += __shfl_xor(s1, m);
      s2 += __shfl_xor(s2, m);
      s3 += __shfl_xor(s3, m);
    }
    if (l15 == 0)   // lanes q=0..3: rows (2*wave+jt)*16 + q*4 + {0..3}
      *(float4*)&scr[(wave * 2 + jt) * 16 + q * 4] = (float4){s0, s1, s2, s3};
  }
  __syncthreads();   // (4) scratch ready
  if (tid < NHID)
    atomicAdd(&msum[batch * NHID + tid], scr[tid]);
}

// ---------------------------------------------------------------------------
// Decoder: 128 blocks = (batch x d2-quarter), 1024 threads. Each block
// computes the full d1 (redundant x4, D1 is L2-resident), its 128-wide d2
// quarter, and atomicAdds its partial L3 dot into out (pre-init'd to c3).
// ---------------------------------------------------------------------------
__global__ __launch_bounds__(1024) void decoder(
    const float* __restrict__ msum,
    const float* __restrict__ D1, const float* __restrict__ c1,
    const float* __restrict__ D2, const float* __restrict__ c2,
    const float* __restrict__ D3,
    float* __restrict__ out) {
  __shared__ float p[NHID];
  __shared__ float d1[NDEC];
  __shared__ float d2q[128];
  __shared__ __align__(16) float red[4096];   // 16 KB
  const int b = blockIdx.x >> 2, qd = blockIdx.x & 3, t = threadIdx.x;

  if (t < NHID) {
    float m = msum[b * NHID + t] * (1.f / NTOK);
    p[t] = m * m;                        // relu(m^2) == m^2
  }
  __syncthreads();

  // ---- layer 1 (full, redundant x4): K = 256 -> 32 k per split ----
  {
    const int jg = t & 127;              // j-group of 4
    const int ks = t >> 7;               // 0..7 K-split
    const float4* D1v = (const float4*)D1;   // [256][128] float4
    float4 s = {0.f, 0.f, 0.f, 0.f};
    for (int k = ks * 32; k < ks * 32 + 32; ++k) {
      float4 w = D1v[k * 128 + jg];
      float pv = p[k];
      s.x += pv * w.x; s.y += pv * w.y; s.z += pv * w.z; s.w += pv * w.w;
    }
    *(float4*)&red[t * 4] = s;
    __syncthreads();
    if (t < NDEC) {
      float v = c1[t];
#pragma unroll
      for (int i = 0; i < 8; ++i) v += red[i * 512 + t];
      d1[t] = fmaxf(v, 0.f);
    }
    __syncthreads();
  }

  // ---- layer 2 (quarter): 128 outs, K = 512 -> 32 splits x 16 k ----
  {
    const int jg2 = t & 31;              // float4 group within quarter
    const int ks2 = t >> 5;              // 0..31 K-split
    const float4* D2v = (const float4*)D2;   // [512][128] float4
    float4 s = {0.f, 0.f, 0.f, 0.f};
    for (int k = ks2 * 16; k < ks2 * 16 + 16; ++k) {
      float4 w = D2v[k * 128 + qd * 32 + jg2];
      float hv = d1[k];
      s.x += hv * w.x; s.y += hv * w.y; s.z += hv * w.z; s.w += hv * w.w;
    }
    *(float4*)&red[t * 4] = s;           // == red[ks2*128 + jg2*4 + c]
    __syncthreads();
    if (t < 128) {
      float v = c2[qd * 128 + t];
#pragma unroll
      for (int i = 0; i < 32; ++i) v += red[i * 128 + t];
      d2q[t] = fmaxf(v, 0.f);
    }
    __syncthreads();
  }

  // ---- layer 3 partial: quarter K = 128; 64 k-chunks x 16 j-slots ----
  {
    const int j3 = t & 15;
    const int kc = t >> 4;               // 0..63, 2 k's each
    float s = 0.f;
    if (j3 < NOUTC)
      for (int k = kc * 2; k < kc * 2 + 2; ++k)
        s += d2q[k] * D3[(qd * 128 + k) * NOUTC + j3];
    red[t] = s;
    __syncthreads();
    if (t < NOUTC) {
      float v = 0.f;
#pragma unroll
      for (int i = 0; i < 64; ++i) v += red[i * 16 + t];
      atomicAdd(&out[b * NOUTC + t], v);
    }
  }
}

// ---------------------------------------------------------------------------
extern "C" void kernel_launch(void* const* d_in, const int* in_sizes, int n_in,
                              void* d_out, int out_size, void* d_ws, size_t ws_size,
                              hipStream_t stream) {
  const float* x  = (const float*)d_in[0];
  const float* W1 = (const float*)d_in[1];
  const float* b1 = (const float*)d_in[2];
  const float* W2 = (const float*)d_in[3];
  const float* b2 = (const float*)d_in[4];
  const float* W3 = (const float*)d_in[5];
  const float* b3 = (const float*)d_in[6];
  const float* D1 = (const float*)d_in[7];
  const float* c1 = (const float*)d_in[8];
  const float* D2 = (const float*)d_in[9];
  const float* c2 = (const float*)d_in[10];
  const float* D3 = (const float*)d_in[11];
  const float* c3 = (const float*)d_in[12];

  // ws: [0,64K) bf16 W1 | [64K,128K) fp8 W2 | [128K,192K) fp8 W3 |
  //     [384K,416K) msum
  uint8_t* pW   = (uint8_t*)d_ws;
  float*   msum = (float*)((char*)d_ws + 384 * 1024);

  pack_weights<<<640, 256, 0, stream>>>(W1, W2, W3, c3, pW, msum,
                                        (float*)d_out);
  encoder<<<NBLK, 512, 0, stream>>>(x, pW, b1, b2, b3, msum);
  decoder<<<128, 1024, 0, stream>>>(msum, D1, c1, D2, c2, D3,
                                    (float*)d_out);
}

// Round 10
// 153.882 us; speedup vs baseline: 1.1518x; 1.0081x over previous
//
#include <hip/hip_runtime.h>
#include <hip/hip_bf16.h>
#include <stdint.h>

// ---------------------------------------------------------------------------
// TensorNet: fused encoder MLP (128->256->256->256, relu) over 32x4096 tokens,
// per-batch mean -> p = relu(m^2) -> decoder MLP (256->512->512->10).
//
// R25: continue the validated LDS-pipe ledger (R24: conflicts 5.8M->2.6M,
// encoder 55->50.7us as predicted).
//  - epilogue butterfly (256 ds_bpermute ops/block ~= 1500 cyc DS pipe;
//    __shfl_xor is DS-pipe on CDNA) -> R17-style padded scratch reduce:
//    16 b128 writes + 64 b32 reads (2-way banks, free) + coalesced atomics.
//    Scratch (17408B) overlays dead h1 buffer + 1KB tail; no extra barrier.
//  - fragment-major W2/W3 packing: a-loads become 8 longx2 (b128) instead
//    of 16 b64 global loads per wave per fp8 layer.
// Unchanged: 512thr/8wave, acc[2][4]=32 VGPR, fp8 e4m3 L2/L3, fragment-
// major fp8 h tiles, SW2 16-slot swizzle, h1 double-buffer, 4 barriers.
//
// HARD RULES from the log:
//  - NEVER pass a min-waves arg to __launch_bounds__ (R5, R19, R22: spills).
//  - NEVER grow per-wave a-load count for "sharing" (R18: 185us).
//  - NEVER shrink MTILE / grow block count (R20).
//  - Occupancy is NOT the lever (R23: +39% waves -> -0.7%); LDS-pipe and
//    serial-chain cycles are (R17, R24).
// Rejected: MTILE=128 (R16), MTILE=48 (R20), wave->token remap (R18),
// direct-global B-frags (R5/R6), ping-pong (R13), cooperative (R11),
// decoder-in-encoder (R14/R15), fp8 x/W1 (absmax risk: current 2.44e-4
// floor is suspected bf16-x dominated; not worth ~1.5us).
// ---------------------------------------------------------------------------

#define NIN   128
#define NHID  256
#define NDEC  512
#define NOUTC 10
#define BATCH 32
#define NTOK  4096
#define MTILE 64
#define NBLK  (BATCH * (NTOK / MTILE))   // 2048 encoder tiles

#define SW2(t) (((t) & 15) << 4)         // XOR swizzle, byte bits 4-7

typedef short bf16x8 __attribute__((ext_vector_type(8)));
typedef float floatx4 __attribute__((ext_vector_type(4)));
typedef long  longx2  __attribute__((ext_vector_type(2)));

__device__ __forceinline__ uint16_t f2b(float f) {
  union { uint32_t u; float f; } v; v.f = f;
  uint32_t r = v.u + 0x7FFFu + ((v.u >> 16) & 1u);   // RNE
  return (uint16_t)(r >> 16);
}
__device__ __forceinline__ uint32_t pkbf(float lo, float hi) {
  __hip_bfloat162 h = __float22bfloat162_rn(float2{lo, hi});  // v_cvt_pk_bf16_f32
  union { __hip_bfloat162 h; uint32_t u; } c; c.h = h;
  return c.u;
}

// ---------------------------------------------------------------------------
// Pack weights: W1 -> bf16 MFMA-A frags (bytes [0,64K)). W2/W3 -> fp8 e4m3
// FRAGMENT-MAJOR ([64K,128K) / [128K,192K)): byte (mt*64+ln)*64 + kc*8 + j,
// so one b128 load at (mt*64+ln)*64 + kc2*16 yields kc=2*kc2, 2*kc2+1.
// Also zero-inits msum and pre-loads out with c3 (stream-ordered).
// ---------------------------------------------------------------------------
__global__ __launch_bounds__(256) void pack_weights(
    const float* __restrict__ W1, const float* __restrict__ W2,
    const float* __restrict__ W3, const float* __restrict__ c3,
    uint8_t* __restrict__ pW, float* __restrict__ msum,
    float* __restrict__ out) {
  int p = blockIdx.x * blockDim.x + threadIdx.x;
  if (p < BATCH * NHID) msum[p] = 0.f;
  if (p < BATCH * NOUTC) out[p] = c3[p % NOUTC];
  if (p < 32768) {
    // W1: K=128, KC=4, bf16, kc-major (one b128 = one kc frag)
    int j = p & 7, ln = (p >> 3) & 63, rest = p >> 9;
    int kc = rest & 3, mt = rest >> 2;
    int m = mt * 16 + (ln & 15);
    int k = kc * 32 + ((ln >> 4) << 3) + j;
    ((uint16_t*)pW)[p] = f2b(W1[k * NHID + m]);
  } else {
    int p2 = p - 32768;
    const float* W = (p2 < 65536) ? W2 : W3;
    int base = (p2 < 65536) ? 65536 : 131072;
    if (p2 >= 65536) p2 -= 65536;
    // K=256, KC=8, fp8 e4m3, fragment-major
    int j = p2 & 7, ln = (p2 >> 3) & 63, rest = p2 >> 9;
    int kc = rest & 7, mt = rest >> 3;
    int m = mt * 16 + (ln & 15);
    int k = kc * 32 + ((ln >> 4) << 3) + j;
    int r = __builtin_amdgcn_cvt_pk_fp8_f32(W[k * NHID + m], 0.f, 0, false);
    pW[base + (mt * 64 + ln) * 64 + kc * 8 + j] = (uint8_t)(r & 0xFF);
  }
}

// ---------------------------------------------------------------------------
// Fused encoder. Block = 512 thr (8 waves), 64 tokens. Wave w owns hidden
// rows [32w,32w+32). HsAll: [0,16K) x tile then h2; [16K,32K) h1; epilogue
// scratch overlays [16K,33792). 4 barriers.
// ---------------------------------------------------------------------------
__global__ __launch_bounds__(512) void encoder(
    const float* __restrict__ x,        // [BATCH*NTOK][NIN] fp32
    const uint8_t* __restrict__ pW,
    const float* __restrict__ b1,
    const float* __restrict__ b2,
    const float* __restrict__ b3,
    float* __restrict__ msum) {         // [BATCH][NHID] fp32 accum
  __shared__ __align__(16) uint8_t HsAll[33792];
  uint8_t* Hs0 = HsAll;                 // 16384 B: x (bf16), then h2 (fp8)
  uint8_t* Hs1 = HsAll + 16384;         // 16384 B: h1 (fp8)

  const int tid  = threadIdx.x;
  const int wave = tid >> 6;
  const int lane = tid & 63;
  const int l15  = lane & 15;
  const int q    = lane >> 4;
  const int tok0  = blockIdx.x * MTILE;
  const int batch = blockIdx.x >> 6;          // 64 tiles per batch

  const uint16_t* pW1 = (const uint16_t*)pW;  // bf16 frags, KC=4
  const uint8_t*  pW2 = pW + 65536;           // fp8 frags, fragment-major
  const uint8_t*  pW3 = pW + 131072;          // fp8 frags, fragment-major

  // ---- stage x tile: 64 tok x 128 ch fp32 -> bf16, row 256B, SW2 ----
  {
    const float4* xv = (const float4*)(x + (size_t)tok0 * NIN);
#pragma unroll
    for (int i = 0; i < 2; ++i) {
      const int u = tid + i * 512;            // 8-float unit, 0..1023
      float4 va = xv[2 * u];
      float4 vb = xv[2 * u + 1];
      uint4 w = make_uint4(pkbf(va.x, va.y), pkbf(va.z, va.w),
                           pkbf(vb.x, vb.y), pkbf(vb.z, vb.w));
      const int row = u >> 4;                 // token 0..63
      const int cb  = (u & 15) << 4;          // byte col 0..240
      *(uint4*)&Hs0[row * 256 + (cb ^ SW2(row))] = w;
    }
  }
  __syncthreads();   // (1) x staged

  floatx4 acc[2][4];   // [jt][tt]

  // ---- layer 1: K = 128 bf16, A = W1^T, B = x(Hs0); acc init = bias ----
#pragma unroll
  for (int jt = 0; jt < 2; ++jt) {
    const float4 bb = *(const float4*)&b1[(wave * 2 + jt) * 16 + q * 4];
#pragma unroll
    for (int tt = 0; tt < 4; ++tt)
      acc[jt][tt] = (floatx4){bb.x, bb.y, bb.z, bb.w};
  }
#pragma unroll
  for (int kc = 0; kc < 4; ++kc) {
    bf16x8 a0 = *(const bf16x8*)(pW1 + ((((wave * 2 + 0) * 4 + kc) * 64 + lane) << 3));
    bf16x8 a1 = *(const bf16x8*)(pW1 + ((((wave * 2 + 1) * 4 + kc) * 64 + lane) << 3));
#pragma unroll
    for (int tt = 0; tt < 4; ++tt) {
      const int t = tt * 16 + l15;
      bf16x8 b = *(const bf16x8*)&Hs0[t * 256 + ((kc * 64 + q * 16) ^ SW2(t))];
      acc[0][tt] = __builtin_amdgcn_mfma_f32_16x16x32_bf16(a0, b, acc[0][tt], 0, 0, 0);
      acc[1][tt] = __builtin_amdgcn_mfma_f32_16x16x32_bf16(a1, b, acc[1][tt], 0, 0, 0);
    }
  }
  // h1 -> Hs1 (fragment-major fp8); no barrier needed (different buffer)
#pragma unroll
  for (int jt = 0; jt < 2; ++jt) {
    const int j0 = (wave * 2 + jt) * 16 + q * 4;
    const int pb = ((j0 >> 3) & 3) * 64 + (j0 >> 5) * 8 + (j0 & 7);
#pragma unroll
    for (int tt = 0; tt < 4; ++tt) {
      const int t = tt * 16 + l15;
      float v0 = fmaxf(acc[jt][tt][0], 0.f);
      float v1 = fmaxf(acc[jt][tt][1], 0.f);
      float v2 = fmaxf(acc[jt][tt][2], 0.f);
      float v3 = fmaxf(acc[jt][tt][3], 0.f);
      int u = __builtin_amdgcn_cvt_pk_fp8_f32(v0, v1, 0, false);
      u = __builtin_amdgcn_cvt_pk_fp8_f32(v2, v3, u, true);
      *(uint32_t*)&Hs1[t * 256 + (pb ^ SW2(t))] = (uint32_t)u;
    }
  }
  __syncthreads();   // (2) h1 complete (implies all x reads done too)

  // ---- layer 2: K = 256 fp8, A = W2^T (fragment-major), B = h1(Hs1) ----
#pragma unroll
  for (int jt = 0; jt < 2; ++jt) {
    const float4 bb = *(const float4*)&b2[(wave * 2 + jt) * 16 + q * 4];
#pragma unroll
    for (int tt = 0; tt < 4; ++tt)
      acc[jt][tt] = (floatx4){bb.x, bb.y, bb.z, bb.w};
  }
#pragma unroll
  for (int kc2 = 0; kc2 < 4; ++kc2) {
    longx2 a0 = *(const longx2*)(pW2 + ((wave * 2 + 0) * 64 + lane) * 64 + kc2 * 16);
    longx2 a1 = *(const longx2*)(pW2 + ((wave * 2 + 1) * 64 + lane) * 64 + kc2 * 16);
    longx2 b[4];
#pragma unroll
    for (int tt = 0; tt < 4; ++tt) {
      const int t = tt * 16 + l15;
      b[tt] = *(const longx2*)&Hs1[t * 256 + ((q * 64 + kc2 * 16) ^ SW2(t))];
    }
#pragma unroll
    for (int s = 0; s < 2; ++s) {
#pragma unroll
      for (int tt = 0; tt < 4; ++tt) {
        acc[0][tt] = __builtin_amdgcn_mfma_f32_16x16x32_fp8_fp8(a0[s], b[tt][s], acc[0][tt], 0, 0, 0);
        acc[1][tt] = __builtin_amdgcn_mfma_f32_16x16x32_fp8_fp8(a1[s], b[tt][s], acc[1][tt], 0, 0, 0);
      }
    }
  }
  // h2 -> Hs0 (x is dead: barrier (2) proved all x reads finished)
#pragma unroll
  for (int jt = 0; jt < 2; ++jt) {
    const int j0 = (wave * 2 + jt) * 16 + q * 4;
    const int pb = ((j0 >> 3) & 3) * 64 + (j0 >> 5) * 8 + (j0 & 7);
#pragma unroll
    for (int tt = 0; tt < 4; ++tt) {
      const int t = tt * 16 + l15;
      float v0 = fmaxf(acc[jt][tt][0], 0.f);
      float v1 = fmaxf(acc[jt][tt][1], 0.f);
      float v2 = fmaxf(acc[jt][tt][2], 0.f);
      float v3 = fmaxf(acc[jt][tt][3], 0.f);
      int u = __builtin_amdgcn_cvt_pk_fp8_f32(v0, v1, 0, false);
      u = __builtin_amdgcn_cvt_pk_fp8_f32(v2, v3, u, true);
      *(uint32_t*)&Hs0[t * 256 + (pb ^ SW2(t))] = (uint32_t)u;
    }
  }
  __syncthreads();   // (3) h2 complete (implies all h1 reads done -> Hs1 dead)

  // ---- layer 3: K = 256 fp8, A = W3^T (fragment-major), B = h2(Hs0) ----
#pragma unroll
  for (int jt = 0; jt < 2; ++jt) {
    const float4 bb = *(const float4*)&b3[(wave * 2 + jt) * 16 + q * 4];
#pragma unroll
    for (int tt = 0; tt < 4; ++tt)
      acc[jt][tt] = (floatx4){bb.x, bb.y, bb.z, bb.w};
  }
#pragma unroll
  for (int kc2 = 0; kc2 < 4; ++kc2) {
    longx2 a0 = *(const longx2*)(pW3 + ((wave * 2 + 0) * 64 + lane) * 64 + kc2 * 16);
    longx2 a1 = *(const longx2*)(pW3 + ((wave * 2 + 1) * 64 + lane) * 64 + kc2 * 16);
    longx2 b[4];
#pragma unroll
    for (int tt = 0; tt < 4; ++tt) {
      const int t = tt * 16 + l15;
      b[tt] = *(const longx2*)&Hs0[t * 256 + ((q * 64 + kc2 * 16) ^ SW2(t))];
    }
#pragma unroll
    for (int s = 0; s < 2; ++s) {
#pragma unroll
      for (int tt = 0; tt < 4; ++tt) {
        acc[0][tt] = __builtin_amdgcn_mfma_f32_16x16x32_fp8_fp8(a0[s], b[tt][s], acc[0][tt], 0, 0, 0);
        acc[1][tt] = __builtin_amdgcn_mfma_f32_16x16x32_fp8_fp8(a1[s], b[tt][s], acc[1][tt], 0, 0, 0);
      }
    }
  }

  // relu + token-sum epilogue, scratch-based (no DS-pipe shuffles):
  // each lane writes its float4 partial to scratch row (wave*2+jt)*4+q,
  // slot l15; rows padded to 17 float4 so the strided reader is 2-way.
  // Scratch overlays Hs1 + 1KB tail (dead since barrier (3)); L3 read Hs0
  // only, so no extra barrier before the writes.
  {
    float4* scratch = (float4*)(HsAll + 16384);   // 64 rows x 17 float4
#pragma unroll
    for (int jt = 0; jt < 2; ++jt) {
      float s0 = 0.f, s1 = 0.f, s2 = 0.f, s3 = 0.f;
#pragma unroll
      for (int tt = 0; tt < 4; ++tt) {
        s0 += fmaxf(acc[jt][tt][0], 0.f);
        s1 += fmaxf(acc[jt][tt][1], 0.f);
        s2 += fmaxf(acc[jt][tt][2], 0.f);
        s3 += fmaxf(acc[jt][tt][3], 0.f);
      }
      scratch[((wave * 2 + jt) * 4 + q) * 17 + l15] = (float4){s0, s1, s2, s3};
    }
  }
  __syncthreads();   // (4) scratch ready
  if (tid < NHID) {
    // hidden j = tid: row = (j>>4)*4 + ((j>>2)&3), elem r = j&3
    const float* sf = (const float*)(HsAll + 16384);
    const int row = ((tid >> 4) << 2) + ((tid >> 2) & 3);
    const int r = tid & 3;
    float v = 0.f;
#pragma unroll
    for (int l = 0; l < 16; ++l)
      v += sf[row * 68 + l * 4 + r];
    atomicAdd(&msum[batch * NHID + tid], v);
  }
}

// ---------------------------------------------------------------------------
// Decoder: 128 blocks = (batch x d2-quarter), 1024 threads. Each block
// computes the full d1 (redundant x4, D1 is L2-resident), its 128-wide d2
// quarter, and atomicAdds its partial L3 dot into out (pre-init'd to c3).
// ---------------------------------------------------------------------------
__global__ __launch_bounds__(1024) void decoder(
    const float* __restrict__ msum,
    const float* __restrict__ D1, const float* __restrict__ c1,
    const float* __restrict__ D2, const float* __restrict__ c2,
    const float* __restrict__ D3,
    float* __restrict__ out) {
  __shared__ float p[NHID];
  __shared__ float d1[NDEC];
  __shared__ float d2q[128];
  __shared__ __align__(16) float red[4096];   // 16 KB
  const int b = blockIdx.x >> 2, qd = blockIdx.x & 3, t = threadIdx.x;

  if (t < NHID) {
    float m = msum[b * NHID + t] * (1.f / NTOK);
    p[t] = m * m;                        // relu(m^2) == m^2
  }
  __syncthreads();

  // ---- layer 1 (full, redundant x4): K = 256 -> 32 k per split ----
  {
    const int jg = t & 127;              // j-group of 4
    const int ks = t >> 7;               // 0..7 K-split
    const float4* D1v = (const float4*)D1;   // [256][128] float4
    float4 s = {0.f, 0.f, 0.f, 0.f};
    for (int k = ks * 32; k < ks * 32 + 32; ++k) {
      float4 w = D1v[k * 128 + jg];
      float pv = p[k];
      s.x += pv * w.x; s.y += pv * w.y; s.z += pv * w.z; s.w += pv * w.w;
    }
    *(float4*)&red[t * 4] = s;
    __syncthreads();
    if (t < NDEC) {
      float v = c1[t];
#pragma unroll
      for (int i = 0; i < 8; ++i) v += red[i * 512 + t];
      d1[t] = fmaxf(v, 0.f);
    }
    __syncthreads();
  }

  // ---- layer 2 (quarter): 128 outs, K = 512 -> 32 splits x 16 k ----
  {
    const int jg2 = t & 31;              // float4 group within quarter
    const int ks2 = t >> 5;              // 0..31 K-split
    const float4* D2v = (const float4*)D2;   // [512][128] float4
    float4 s = {0.f, 0.f, 0.f, 0.f};
    for (int k = ks2 * 16; k < ks2 * 16 + 16; ++k) {
      float4 w = D2v[k * 128 + qd * 32 + jg2];
      float hv = d1[k];
      s.x += hv * w.x; s.y += hv * w.y; s.z += hv * w.z; s.w += hv * w.w;
    }
    *(float4*)&red[t * 4] = s;           // == red[ks2*128 + jg2*4 + c]
    __syncthreads();
    if (t < 128) {
      float v = c2[qd * 128 + t];
#pragma unroll
      for (int i = 0; i < 32; ++i) v += red[i * 128 + t];
      d2q[t] = fmaxf(v, 0.f);
    }
    __syncthreads();
  }

  // ---- layer 3 partial: quarter K = 128; 64 k-chunks x 16 j-slots ----
  {
    const int j3 = t & 15;
    const int kc = t >> 4;               // 0..63, 2 k's each
    float s = 0.f;
    if (j3 < NOUTC)
      for (int k = kc * 2; k < kc * 2 + 2; ++k)
        s += d2q[k] * D3[(qd * 128 + k) * NOUTC + j3];
    red[t] = s;
    __syncthreads();
    if (t < NOUTC) {
      float v = 0.f;
#pragma unroll
      for (int i = 0; i < 64; ++i) v += red[i * 16 + t];
      atomicAdd(&out[b * NOUTC + t], v);
    }
  }
}

// ---------------------------------------------------------------------------
extern "C" void kernel_launch(void* const* d_in, const int* in_sizes, int n_in,
                              void* d_out, int out_size, void* d_ws, size_t ws_size,
                              hipStream_t stream) {
  const float* x  = (const float*)d_in[0];
  const float* W1 = (const float*)d_in[1];
  const float* b1 = (const float*)d_in[2];
  const float* W2 = (const float*)d_in[3];
  const float* b2 = (const float*)d_in[4];
  const float* W3 = (const float*)d_in[5];
  const float* b3 = (const float*)d_in[6];
  const float* D1 = (const float*)d_in[7];
  const float* c1 = (const float*)d_in[8];
  const float* D2 = (const float*)d_in[9];
  const float* c2 = (const float*)d_in[10];
  const float* D3 = (const float*)d_in[11];
  const float* c3 = (const float*)d_in[12];

  // ws: [0,64K) bf16 W1 | [64K,128K) fp8 W2 | [128K,192K) fp8 W3 |
  //     [384K,416K) msum
  uint8_t* pW   = (uint8_t*)d_ws;
  float*   msum = (float*)((char*)d_ws + 384 * 1024);

  pack_weights<<<640, 256, 0, stream>>>(W1, W2, W3, c3, pW, msum,
                                        (float*)d_out);
  encoder<<<NBLK, 512, 0, stream>>>(x, pW, b1, b2, b3, msum);
  decoder<<<128, 1024, 0, stream>>>(msum, D1, c1, D2, c2, D3,
                                    (float*)d_out);
}

// Round 11
// 152.808 us; speedup vs baseline: 1.1599x; 1.0070x over previous
//
#include <hip/hip_runtime.h>
#include <hip/hip_bf16.h>
#include <stdint.h>

// ---------------------------------------------------------------------------
// TensorNet: fused encoder MLP (128->256->256->256, relu) over 32x4096 tokens,
// per-batch mean -> p = relu(m^2) -> decoder MLP (256->512->512->10).
//
// R26: decoder 128 -> 256 blocks (batch x d2-eighth). Encoder is byte-
// identical to R25 (best: 153.9us total, encoder ~49us) — clean A/B on the
// decoder, the only never-measured component of the constant ~105us
// non-encoder remainder. Decoder is latency-bound (27 MFLOP, 1.3MB weights);
// halving per-block serial work should halve it. d1 redundant x8 costs
// +64MB L2 (~2us chip-wide, D1 L2-resident).
//
// HARD RULES from the log:
//  - NEVER pass a min-waves arg to __launch_bounds__ (R5, R19, R22: spills).
//  - NEVER grow per-wave a-load count for "sharing" (R18: 185us).
//  - NEVER shrink MTILE / grow encoder block count (R20).
//  - Occupancy is NOT the encoder lever (R23); LDS-pipe/serial-chain is
//    (R17, R24, R25 — all predicted correctly).
// Rejected: MTILE=128 (R16), MTILE=48 (R20), wave->token remap (R18),
// direct-global B-frags (R5/R6), ping-pong (R13), cooperative (R11),
// decoder-in-encoder (R14/R15). fp8 x/W1 deferred (absmax 2.44e-4 is pinned
// by the bf16 x-W1 path; fp8 there -> ~4e-3 vs unknown threshold).
// ---------------------------------------------------------------------------

#define NIN   128
#define NHID  256
#define NDEC  512
#define NOUTC 10
#define BATCH 32
#define NTOK  4096
#define MTILE 64
#define NBLK  (BATCH * (NTOK / MTILE))   // 2048 encoder tiles

#define SW2(t) (((t) & 15) << 4)         // XOR swizzle, byte bits 4-7

typedef short bf16x8 __attribute__((ext_vector_type(8)));
typedef float floatx4 __attribute__((ext_vector_type(4)));
typedef long  longx2  __attribute__((ext_vector_type(2)));

__device__ __forceinline__ uint16_t f2b(float f) {
  union { uint32_t u; float f; } v; v.f = f;
  uint32_t r = v.u + 0x7FFFu + ((v.u >> 16) & 1u);   // RNE
  return (uint16_t)(r >> 16);
}
__device__ __forceinline__ uint32_t pkbf(float lo, float hi) {
  __hip_bfloat162 h = __float22bfloat162_rn(float2{lo, hi});  // v_cvt_pk_bf16_f32
  union { __hip_bfloat162 h; uint32_t u; } c; c.h = h;
  return c.u;
}

// ---------------------------------------------------------------------------
// Pack weights: W1 -> bf16 MFMA-A frags (bytes [0,64K)). W2/W3 -> fp8 e4m3
// FRAGMENT-MAJOR ([64K,128K) / [128K,192K)): byte (mt*64+ln)*64 + kc*8 + j,
// so one b128 load at (mt*64+ln)*64 + kc2*16 yields kc=2*kc2, 2*kc2+1.
// Also zero-inits msum and pre-loads out with c3 (stream-ordered).
// ---------------------------------------------------------------------------
__global__ __launch_bounds__(256) void pack_weights(
    const float* __restrict__ W1, const float* __restrict__ W2,
    const float* __restrict__ W3, const float* __restrict__ c3,
    uint8_t* __restrict__ pW, float* __restrict__ msum,
    float* __restrict__ out) {
  int p = blockIdx.x * blockDim.x + threadIdx.x;
  if (p < BATCH * NHID) msum[p] = 0.f;
  if (p < BATCH * NOUTC) out[p] = c3[p % NOUTC];
  if (p < 32768) {
    // W1: K=128, KC=4, bf16, kc-major (one b128 = one kc frag)
    int j = p & 7, ln = (p >> 3) & 63, rest = p >> 9;
    int kc = rest & 3, mt = rest >> 2;
    int m = mt * 16 + (ln & 15);
    int k = kc * 32 + ((ln >> 4) << 3) + j;
    ((uint16_t*)pW)[p] = f2b(W1[k * NHID + m]);
  } else {
    int p2 = p - 32768;
    const float* W = (p2 < 65536) ? W2 : W3;
    int base = (p2 < 65536) ? 65536 : 131072;
    if (p2 >= 65536) p2 -= 65536;
    // K=256, KC=8, fp8 e4m3, fragment-major
    int j = p2 & 7, ln = (p2 >> 3) & 63, rest = p2 >> 9;
    int kc = rest & 7, mt = rest >> 3;
    int m = mt * 16 + (ln & 15);
    int k = kc * 32 + ((ln >> 4) << 3) + j;
    int r = __builtin_amdgcn_cvt_pk_fp8_f32(W[k * NHID + m], 0.f, 0, false);
    pW[base + (mt * 64 + ln) * 64 + kc * 8 + j] = (uint8_t)(r & 0xFF);
  }
}

// ---------------------------------------------------------------------------
// Fused encoder. Block = 512 thr (8 waves), 64 tokens. Wave w owns hidden
// rows [32w,32w+32). HsAll: [0,16K) x tile then h2; [16K,32K) h1; epilogue
// scratch overlays [16K,33792). 4 barriers. (BYTE-IDENTICAL TO R25.)
// ---------------------------------------------------------------------------
__global__ __launch_bounds__(512) void encoder(
    const float* __restrict__ x,        // [BATCH*NTOK][NIN] fp32
    const uint8_t* __restrict__ pW,
    const float* __restrict__ b1,
    const float* __restrict__ b2,
    const float* __restrict__ b3,
    float* __restrict__ msum) {         // [BATCH][NHID] fp32 accum
  __shared__ __align__(16) uint8_t HsAll[33792];
  uint8_t* Hs0 = HsAll;                 // 16384 B: x (bf16), then h2 (fp8)
  uint8_t* Hs1 = HsAll + 16384;         // 16384 B: h1 (fp8)

  const int tid  = threadIdx.x;
  const int wave = tid >> 6;
  const int lane = tid & 63;
  const int l15  = lane & 15;
  const int q    = lane >> 4;
  const int tok0  = blockIdx.x * MTILE;
  const int batch = blockIdx.x >> 6;          // 64 tiles per batch

  const uint16_t* pW1 = (const uint16_t*)pW;  // bf16 frags, KC=4
  const uint8_t*  pW2 = pW + 65536;           // fp8 frags, fragment-major
  const uint8_t*  pW3 = pW + 131072;          // fp8 frags, fragment-major

  // ---- stage x tile: 64 tok x 128 ch fp32 -> bf16, row 256B, SW2 ----
  {
    const float4* xv = (const float4*)(x + (size_t)tok0 * NIN);
#pragma unroll
    for (int i = 0; i < 2; ++i) {
      const int u = tid + i * 512;            // 8-float unit, 0..1023
      float4 va = xv[2 * u];
      float4 vb = xv[2 * u + 1];
      uint4 w = make_uint4(pkbf(va.x, va.y), pkbf(va.z, va.w),
                           pkbf(vb.x, vb.y), pkbf(vb.z, vb.w));
      const int row = u >> 4;                 // token 0..63
      const int cb  = (u & 15) << 4;          // byte col 0..240
      *(uint4*)&Hs0[row * 256 + (cb ^ SW2(row))] = w;
    }
  }
  __syncthreads();   // (1) x staged

  floatx4 acc[2][4];   // [jt][tt]

  // ---- layer 1: K = 128 bf16, A = W1^T, B = x(Hs0); acc init = bias ----
#pragma unroll
  for (int jt = 0; jt < 2; ++jt) {
    const float4 bb = *(const float4*)&b1[(wave * 2 + jt) * 16 + q * 4];
#pragma unroll
    for (int tt = 0; tt < 4; ++tt)
      acc[jt][tt] = (floatx4){bb.x, bb.y, bb.z, bb.w};
  }
#pragma unroll
  for (int kc = 0; kc < 4; ++kc) {
    bf16x8 a0 = *(const bf16x8*)(pW1 + ((((wave * 2 + 0) * 4 + kc) * 64 + lane) << 3));
    bf16x8 a1 = *(const bf16x8*)(pW1 + ((((wave * 2 + 1) * 4 + kc) * 64 + lane) << 3));
#pragma unroll
    for (int tt = 0; tt < 4; ++tt) {
      const int t = tt * 16 + l15;
      bf16x8 b = *(const bf16x8*)&Hs0[t * 256 + ((kc * 64 + q * 16) ^ SW2(t))];
      acc[0][tt] = __builtin_amdgcn_mfma_f32_16x16x32_bf16(a0, b, acc[0][tt], 0, 0, 0);
      acc[1][tt] = __builtin_amdgcn_mfma_f32_16x16x32_bf16(a1, b, acc[1][tt], 0, 0, 0);
    }
  }
  // h1 -> Hs1 (fragment-major fp8); no barrier needed (different buffer)
#pragma unroll
  for (int jt = 0; jt < 2; ++jt) {
    const int j0 = (wave * 2 + jt) * 16 + q * 4;
    const int pb = ((j0 >> 3) & 3) * 64 + (j0 >> 5) * 8 + (j0 & 7);
#pragma unroll
    for (int tt = 0; tt < 4; ++tt) {
      const int t = tt * 16 + l15;
      float v0 = fmaxf(acc[jt][tt][0], 0.f);
      float v1 = fmaxf(acc[jt][tt][1], 0.f);
      float v2 = fmaxf(acc[jt][tt][2], 0.f);
      float v3 = fmaxf(acc[jt][tt][3], 0.f);
      int u = __builtin_amdgcn_cvt_pk_fp8_f32(v0, v1, 0, false);
      u = __builtin_amdgcn_cvt_pk_fp8_f32(v2, v3, u, true);
      *(uint32_t*)&Hs1[t * 256 + (pb ^ SW2(t))] = (uint32_t)u;
    }
  }
  __syncthreads();   // (2) h1 complete (implies all x reads done too)

  // ---- layer 2: K = 256 fp8, A = W2^T (fragment-major), B = h1(Hs1) ----
#pragma unroll
  for (int jt = 0; jt < 2; ++jt) {
    const float4 bb = *(const float4*)&b2[(wave * 2 + jt) * 16 + q * 4];
#pragma unroll
    for (int tt = 0; tt < 4; ++tt)
      acc[jt][tt] = (floatx4){bb.x, bb.y, bb.z, bb.w};
  }
#pragma unroll
  for (int kc2 = 0; kc2 < 4; ++kc2) {
    longx2 a0 = *(const longx2*)(pW2 + ((wave * 2 + 0) * 64 + lane) * 64 + kc2 * 16);
    longx2 a1 = *(const longx2*)(pW2 + ((wave * 2 + 1) * 64 + lane) * 64 + kc2 * 16);
    longx2 b[4];
#pragma unroll
    for (int tt = 0; tt < 4; ++tt) {
      const int t = tt * 16 + l15;
      b[tt] = *(const longx2*)&Hs1[t * 256 + ((q * 64 + kc2 * 16) ^ SW2(t))];
    }
#pragma unroll
    for (int s = 0; s < 2; ++s) {
#pragma unroll
      for (int tt = 0; tt < 4; ++tt) {
        acc[0][tt] = __builtin_amdgcn_mfma_f32_16x16x32_fp8_fp8(a0[s], b[tt][s], acc[0][tt], 0, 0, 0);
        acc[1][tt] = __builtin_amdgcn_mfma_f32_16x16x32_fp8_fp8(a1[s], b[tt][s], acc[1][tt], 0, 0, 0);
      }
    }
  }
  // h2 -> Hs0 (x is dead: barrier (2) proved all x reads finished)
#pragma unroll
  for (int jt = 0; jt < 2; ++jt) {
    const int j0 = (wave * 2 + jt) * 16 + q * 4;
    const int pb = ((j0 >> 3) & 3) * 64 + (j0 >> 5) * 8 + (j0 & 7);
#pragma unroll
    for (int tt = 0; tt < 4; ++tt) {
      const int t = tt * 16 + l15;
      float v0 = fmaxf(acc[jt][tt][0], 0.f);
      float v1 = fmaxf(acc[jt][tt][1], 0.f);
      float v2 = fmaxf(acc[jt][tt][2], 0.f);
      float v3 = fmaxf(acc[jt][tt][3], 0.f);
      int u = __builtin_amdgcn_cvt_pk_fp8_f32(v0, v1, 0, false);
      u = __builtin_amdgcn_cvt_pk_fp8_f32(v2, v3, u, true);
      *(uint32_t*)&Hs0[t * 256 + (pb ^ SW2(t))] = (uint32_t)u;
    }
  }
  __syncthreads();   // (3) h2 complete (implies all h1 reads done -> Hs1 dead)

  // ---- layer 3: K = 256 fp8, A = W3^T (fragment-major), B = h2(Hs0) ----
#pragma unroll
  for (int jt = 0; jt < 2; ++jt) {
    const float4 bb = *(const float4*)&b3[(wave * 2 + jt) * 16 + q * 4];
#pragma unroll
    for (int tt = 0; tt < 4; ++tt)
      acc[jt][tt] = (floatx4){bb.x, bb.y, bb.z, bb.w};
  }
#pragma unroll
  for (int kc2 = 0; kc2 < 4; ++kc2) {
    longx2 a0 = *(const longx2*)(pW3 + ((wave * 2 + 0) * 64 + lane) * 64 + kc2 * 16);
    longx2 a1 = *(const longx2*)(pW3 + ((wave * 2 + 1) * 64 + lane) * 64 + kc2 * 16);
    longx2 b[4];
#pragma unroll
    for (int tt = 0; tt < 4; ++tt) {
      const int t = tt * 16 + l15;
      b[tt] = *(const longx2*)&Hs0[t * 256 + ((q * 64 + kc2 * 16) ^ SW2(t))];
    }
#pragma unroll
    for (int s = 0; s < 2; ++s) {
#pragma unroll
      for (int tt = 0; tt < 4; ++tt) {
        acc[0][tt] = __builtin_amdgcn_mfma_f32_16x16x32_fp8_fp8(a0[s], b[tt][s], acc[0][tt], 0, 0, 0);
        acc[1][tt] = __builtin_amdgcn_mfma_f32_16x16x32_fp8_fp8(a1[s], b[tt][s], acc[1][tt], 0, 0, 0);
      }
    }
  }

  // relu + token-sum epilogue, scratch-based (no DS-pipe shuffles).
  {
    float4* scratch = (float4*)(HsAll + 16384);   // 64 rows x 17 float4
#pragma unroll
    for (int jt = 0; jt < 2; ++jt) {
      float s0 = 0.f, s1 = 0.f, s2 = 0.f, s3 = 0.f;
#pragma unroll
      for (int tt = 0; tt < 4; ++tt) {
        s0 += fmaxf(acc[jt][tt][0], 0.f);
        s1 += fmaxf(acc[jt][tt][1], 0.f);
        s2 += fmaxf(acc[jt][tt][2], 0.f);
        s3 += fmaxf(acc[jt][tt][3], 0.f);
      }
      scratch[((wave * 2 + jt) * 4 + q) * 17 + l15] = (float4){s0, s1, s2, s3};
    }
  }
  __syncthreads();   // (4) scratch ready
  if (tid < NHID) {
    // hidden j = tid: row = (j>>4)*4 + ((j>>2)&3), elem r = j&3
    const float* sf = (const float*)(HsAll + 16384);
    const int row = ((tid >> 4) << 2) + ((tid >> 2) & 3);
    const int r = tid & 3;
    float v = 0.f;
#pragma unroll
    for (int l = 0; l < 16; ++l)
      v += sf[row * 68 + l * 4 + r];
    atomicAdd(&msum[batch * NHID + tid], v);
  }
}

// ---------------------------------------------------------------------------
// Decoder: 256 blocks = (batch x d2-eighth), 1024 threads. Each block
// computes the full d1 (redundant x8, D1 is L2-resident), its 64-wide d2
// eighth, and atomicAdds its partial L3 dot into out (pre-init'd to c3).
// ---------------------------------------------------------------------------
__global__ __launch_bounds__(1024) void decoder(
    const float* __restrict__ msum,
    const float* __restrict__ D1, const float* __restrict__ c1,
    const float* __restrict__ D2, const float* __restrict__ c2,
    const float* __restrict__ D3,
    float* __restrict__ out) {
  __shared__ float p[NHID];
  __shared__ float d1[NDEC];
  __shared__ float d2e[64];
  __shared__ __align__(16) float red[4096];   // 16 KB
  const int b = blockIdx.x >> 3, qd = blockIdx.x & 7, t = threadIdx.x;

  if (t < NHID) {
    float m = msum[b * NHID + t] * (1.f / NTOK);
    p[t] = m * m;                        // relu(m^2) == m^2
  }
  __syncthreads();

  // ---- layer 1 (full, redundant x8): K = 256 -> 32 k per split ----
  {
    const int jg = t & 127;              // j-group of 4
    const int ks = t >> 7;               // 0..7 K-split
    const float4* D1v = (const float4*)D1;   // [256][128] float4
    float4 s = {0.f, 0.f, 0.f, 0.f};
    for (int k = ks * 32; k < ks * 32 + 32; ++k) {
      float4 w = D1v[k * 128 + jg];
      float pv = p[k];
      s.x += pv * w.x; s.y += pv * w.y; s.z += pv * w.z; s.w += pv * w.w;
    }
    *(float4*)&red[t * 4] = s;
    __syncthreads();
    if (t < NDEC) {
      float v = c1[t];
#pragma unroll
      for (int i = 0; i < 8; ++i) v += red[i * 512 + t];
      d1[t] = fmaxf(v, 0.f);
    }
    __syncthreads();
  }

  // ---- layer 2 (eighth): 64 outs, K = 512 -> 64 splits x 8 k ----
  {
    const int jg2 = t & 15;              // float4 group within eighth
    const int ks2 = t >> 4;              // 0..63 K-split
    const float4* D2v = (const float4*)D2;   // [512][128] float4
    float4 s = {0.f, 0.f, 0.f, 0.f};
    for (int k = ks2 * 8; k < ks2 * 8 + 8; ++k) {
      float4 w = D2v[k * 128 + qd * 16 + jg2];
      float hv = d1[k];
      s.x += hv * w.x; s.y += hv * w.y; s.z += hv * w.z; s.w += hv * w.w;
    }
    *(float4*)&red[t * 4] = s;           // == red[ks2*64 + jg2*4 + c]
    __syncthreads();
    if (t < 64) {
      float v = c2[qd * 64 + t];
#pragma unroll
      for (int i = 0; i < 64; ++i) v += red[i * 64 + t];
      d2e[t] = fmaxf(v, 0.f);
    }
    __syncthreads();
  }

  // ---- layer 3 partial: eighth K = 64; 64 k-chunks x 16 j-slots ----
  {
    const int j3 = t & 15;
    const int kc = t >> 4;               // 0..63, 1 k each
    float s = 0.f;
    if (j3 < NOUTC)
      s = d2e[kc] * D3[(qd * 64 + kc) * NOUTC + j3];
    red[t] = s;
    __syncthreads();
    if (t < NOUTC) {
      float v = 0.f;
#pragma unroll
      for (int i = 0; i < 64; ++i) v += red[i * 16 + t];
      atomicAdd(&out[b * NOUTC + t], v);
    }
  }
}

// ---------------------------------------------------------------------------
extern "C" void kernel_launch(void* const* d_in, const int* in_sizes, int n_in,
                              void* d_out, int out_size, void* d_ws, size_t ws_size,
                              hipStream_t stream) {
  const float* x  = (const float*)d_in[0];
  const float* W1 = (const float*)d_in[1];
  const float* b1 = (const float*)d_in[2];
  const float* W2 = (const float*)d_in[3];
  const float* b2 = (const float*)d_in[4];
  const float* W3 = (const float*)d_in[5];
  const float* b3 = (const float*)d_in[6];
  const float* D1 = (const float*)d_in[7];
  const float* c1 = (const float*)d_in[8];
  const float* D2 = (const float*)d_in[9];
  const float* c2 = (const float*)d_in[10];
  const float* D3 = (const float*)d_in[11];
  const float* c3 = (const float*)d_in[12];

  // ws: [0,64K) bf16 W1 | [64K,128K) fp8 W2 | [128K,192K) fp8 W3 |
  //     [384K,416K) msum
  uint8_t* pW   = (uint8_t*)d_ws;
  float*   msum = (float*)((char*)d_ws + 384 * 1024);

  pack_weights<<<640, 256, 0, stream>>>(W1, W2, W3, c3, pW, msum,
                                        (float*)d_out);
  encoder<<<NBLK, 512, 0, stream>>>(x, pW, b1, b2, b3, msum);
  decoder<<<256, 1024, 0, stream>>>(msum, D1, c1, D2, c2, D3,
                                    (float*)d_out);
}

// Round 12
// 152.436 us; speedup vs baseline: 1.1627x; 1.0024x over previous
//
#include <hip/hip_runtime.h>
#include <hip/hip_bf16.h>
#include <stdint.h>

// ---------------------------------------------------------------------------
// TensorNet: fused encoder MLP (128->256->256->256, relu) over 32x4096 tokens,
// per-batch mean -> p = relu(m^2) -> decoder MLP (256->512->512->10).
//
// R27: encoder micro-pipeline. (R26: decoder split -1.1us; non-encoder
// ~100us is harness-fixed; encoder ~50us is the only remaining term, and is
// latency-bound — HBM 9%, MFMA 33%, DS ~50%, nothing saturated.)
//  - per-layer a-frag prefetch: kc=0 frags loaded BEFORE the preceding
//    barrier (depend only on pW), in-loop a-loads pipelined one kc ahead
//    (explicit na = load(kc+1) before the MFMA group). Kills the 3x
//    ~300cy L2 stall at each layer entry.
//  - s_setprio(1) around each per-kc MFMA group (blocks independent &
//    staggered = the regime where setprio measured +4-7%; R19's trial was
//    spill-confounded, never clean).
// Pack/decoder byte-identical to R26.
//
// HARD RULES from the log:
//  - NEVER pass a min-waves arg to __launch_bounds__ (R5, R19, R22: spills).
//  - NEVER grow per-wave a-load count for "sharing" (R18: 185us).
//  - NEVER shrink MTILE / grow encoder block count (R20).
//  - Occupancy is NOT the encoder lever (R23); LDS-pipe/serial-chain is
//    (R17, R24, R25 — all predicted correctly).
// Watch: VGPR must stay <=64 (cliff); >=66 -> revert this round.
// ---------------------------------------------------------------------------

#define NIN   128
#define NHID  256
#define NDEC  512
#define NOUTC 10
#define BATCH 32
#define NTOK  4096
#define MTILE 64
#define NBLK  (BATCH * (NTOK / MTILE))   // 2048 encoder tiles

#define SW2(t) (((t) & 15) << 4)         // XOR swizzle, byte bits 4-7

typedef short bf16x8 __attribute__((ext_vector_type(8)));
typedef float floatx4 __attribute__((ext_vector_type(4)));
typedef long  longx2  __attribute__((ext_vector_type(2)));

__device__ __forceinline__ uint16_t f2b(float f) {
  union { uint32_t u; float f; } v; v.f = f;
  uint32_t r = v.u + 0x7FFFu + ((v.u >> 16) & 1u);   // RNE
  return (uint16_t)(r >> 16);
}
__device__ __forceinline__ uint32_t pkbf(float lo, float hi) {
  __hip_bfloat162 h = __float22bfloat162_rn(float2{lo, hi});  // v_cvt_pk_bf16_f32
  union { __hip_bfloat162 h; uint32_t u; } c; c.h = h;
  return c.u;
}

// ---------------------------------------------------------------------------
// Pack weights: W1 -> bf16 MFMA-A frags (bytes [0,64K)). W2/W3 -> fp8 e4m3
// FRAGMENT-MAJOR ([64K,128K) / [128K,192K)): byte (mt*64+ln)*64 + kc*8 + j,
// so one b128 load at (mt*64+ln)*64 + kc2*16 yields kc=2*kc2, 2*kc2+1.
// Also zero-inits msum and pre-loads out with c3 (stream-ordered).
// ---------------------------------------------------------------------------
__global__ __launch_bounds__(256) void pack_weights(
    const float* __restrict__ W1, const float* __restrict__ W2,
    const float* __restrict__ W3, const float* __restrict__ c3,
    uint8_t* __restrict__ pW, float* __restrict__ msum,
    float* __restrict__ out) {
  int p = blockIdx.x * blockDim.x + threadIdx.x;
  if (p < BATCH * NHID) msum[p] = 0.f;
  if (p < BATCH * NOUTC) out[p] = c3[p % NOUTC];
  if (p < 32768) {
    // W1: K=128, KC=4, bf16, kc-major (one b128 = one kc frag)
    int j = p & 7, ln = (p >> 3) & 63, rest = p >> 9;
    int kc = rest & 3, mt = rest >> 2;
    int m = mt * 16 + (ln & 15);
    int k = kc * 32 + ((ln >> 4) << 3) + j;
    ((uint16_t*)pW)[p] = f2b(W1[k * NHID + m]);
  } else {
    int p2 = p - 32768;
    const float* W = (p2 < 65536) ? W2 : W3;
    int base = (p2 < 65536) ? 65536 : 131072;
    if (p2 >= 65536) p2 -= 65536;
    // K=256, KC=8, fp8 e4m3, fragment-major
    int j = p2 & 7, ln = (p2 >> 3) & 63, rest = p2 >> 9;
    int kc = rest & 7, mt = rest >> 3;
    int m = mt * 16 + (ln & 15);
    int k = kc * 32 + ((ln >> 4) << 3) + j;
    int r = __builtin_amdgcn_cvt_pk_fp8_f32(W[k * NHID + m], 0.f, 0, false);
    pW[base + (mt * 64 + ln) * 64 + kc * 8 + j] = (uint8_t)(r & 0xFF);
  }
}

// ---------------------------------------------------------------------------
// Fused encoder. Block = 512 thr (8 waves), 64 tokens. Wave w owns hidden
// rows [32w,32w+32). HsAll: [0,16K) x tile then h2; [16K,32K) h1; epilogue
// scratch overlays [16K,33792). 4 barriers. a-frags prefetched across each
// barrier + pipelined one kc ahead; setprio(1) around MFMA groups.
// ---------------------------------------------------------------------------
__global__ __launch_bounds__(512) void encoder(
    const float* __restrict__ x,        // [BATCH*NTOK][NIN] fp32
    const uint8_t* __restrict__ pW,
    const float* __restrict__ b1,
    const float* __restrict__ b2,
    const float* __restrict__ b3,
    float* __restrict__ msum) {         // [BATCH][NHID] fp32 accum
  __shared__ __align__(16) uint8_t HsAll[33792];
  uint8_t* Hs0 = HsAll;                 // 16384 B: x (bf16), then h2 (fp8)
  uint8_t* Hs1 = HsAll + 16384;         // 16384 B: h1 (fp8)

  const int tid  = threadIdx.x;
  const int wave = tid >> 6;
  const int lane = tid & 63;
  const int l15  = lane & 15;
  const int q    = lane >> 4;
  const int tok0  = blockIdx.x * MTILE;
  const int batch = blockIdx.x >> 6;          // 64 tiles per batch

  const uint16_t* pW1 = (const uint16_t*)pW;  // bf16 frags, KC=4
  const uint8_t*  pW2 = pW + 65536;           // fp8 frags, fragment-major
  const uint8_t*  pW3 = pW + 131072;          // fp8 frags, fragment-major

  // ---- stage x tile: 64 tok x 128 ch fp32 -> bf16, row 256B, SW2 ----
  {
    const float4* xv = (const float4*)(x + (size_t)tok0 * NIN);
#pragma unroll
    for (int i = 0; i < 2; ++i) {
      const int u = tid + i * 512;            // 8-float unit, 0..1023
      float4 va = xv[2 * u];
      float4 vb = xv[2 * u + 1];
      uint4 w = make_uint4(pkbf(va.x, va.y), pkbf(va.z, va.w),
                           pkbf(vb.x, vb.y), pkbf(vb.z, vb.w));
      const int row = u >> 4;                 // token 0..63
      const int cb  = (u & 15) << 4;          // byte col 0..240
      *(uint4*)&Hs0[row * 256 + (cb ^ SW2(row))] = w;
    }
  }
  // prefetch L1 kc=0 a-frags before the barrier (pW-only dependency)
  bf16x8 a0 = *(const bf16x8*)(pW1 + ((((wave * 2 + 0) * 4 + 0) * 64 + lane) << 3));
  bf16x8 a1 = *(const bf16x8*)(pW1 + ((((wave * 2 + 1) * 4 + 0) * 64 + lane) << 3));
  __syncthreads();   // (1) x staged

  floatx4 acc[2][4];   // [jt][tt]

  // ---- layer 1: K = 128 bf16, A = W1^T, B = x(Hs0); acc init = bias ----
#pragma unroll
  for (int jt = 0; jt < 2; ++jt) {
    const float4 bb = *(const float4*)&b1[(wave * 2 + jt) * 16 + q * 4];
#pragma unroll
    for (int tt = 0; tt < 4; ++tt)
      acc[jt][tt] = (floatx4){bb.x, bb.y, bb.z, bb.w};
  }
#pragma unroll
  for (int kc = 0; kc < 4; ++kc) {
    bf16x8 na0, na1;
    if (kc < 3) {
      na0 = *(const bf16x8*)(pW1 + ((((wave * 2 + 0) * 4 + kc + 1) * 64 + lane) << 3));
      na1 = *(const bf16x8*)(pW1 + ((((wave * 2 + 1) * 4 + kc + 1) * 64 + lane) << 3));
    }
    bf16x8 b[4];
#pragma unroll
    for (int tt = 0; tt < 4; ++tt) {
      const int t = tt * 16 + l15;
      b[tt] = *(const bf16x8*)&Hs0[t * 256 + ((kc * 64 + q * 16) ^ SW2(t))];
    }
    __builtin_amdgcn_s_setprio(1);
#pragma unroll
    for (int tt = 0; tt < 4; ++tt) {
      acc[0][tt] = __builtin_amdgcn_mfma_f32_16x16x32_bf16(a0, b[tt], acc[0][tt], 0, 0, 0);
      acc[1][tt] = __builtin_amdgcn_mfma_f32_16x16x32_bf16(a1, b[tt], acc[1][tt], 0, 0, 0);
    }
    __builtin_amdgcn_s_setprio(0);
    if (kc < 3) { a0 = na0; a1 = na1; }
  }
  // h1 -> Hs1 (fragment-major fp8); no barrier needed (different buffer)
#pragma unroll
  for (int jt = 0; jt < 2; ++jt) {
    const int j0 = (wave * 2 + jt) * 16 + q * 4;
    const int pb = ((j0 >> 3) & 3) * 64 + (j0 >> 5) * 8 + (j0 & 7);
#pragma unroll
    for (int tt = 0; tt < 4; ++tt) {
      const int t = tt * 16 + l15;
      float v0 = fmaxf(acc[jt][tt][0], 0.f);
      float v1 = fmaxf(acc[jt][tt][1], 0.f);
      float v2 = fmaxf(acc[jt][tt][2], 0.f);
      float v3 = fmaxf(acc[jt][tt][3], 0.f);
      int u = __builtin_amdgcn_cvt_pk_fp8_f32(v0, v1, 0, false);
      u = __builtin_amdgcn_cvt_pk_fp8_f32(v2, v3, u, true);
      *(uint32_t*)&Hs1[t * 256 + (pb ^ SW2(t))] = (uint32_t)u;
    }
  }
  // prefetch L2 kc2=0 a-frags before the barrier
  longx2 A0 = *(const longx2*)(pW2 + ((wave * 2 + 0) * 64 + lane) * 64);
  longx2 A1 = *(const longx2*)(pW2 + ((wave * 2 + 1) * 64 + lane) * 64);
  __syncthreads();   // (2) h1 complete (implies all x reads done too)

  // ---- layer 2: K = 256 fp8, A = W2^T (fragment-major), B = h1(Hs1) ----
#pragma unroll
  for (int jt = 0; jt < 2; ++jt) {
    const float4 bb = *(const float4*)&b2[(wave * 2 + jt) * 16 + q * 4];
#pragma unroll
    for (int tt = 0; tt < 4; ++tt)
      acc[jt][tt] = (floatx4){bb.x, bb.y, bb.z, bb.w};
  }
#pragma unroll
  for (int kc2 = 0; kc2 < 4; ++kc2) {
    longx2 nA0, nA1;
    if (kc2 < 3) {
      nA0 = *(const longx2*)(pW2 + ((wave * 2 + 0) * 64 + lane) * 64 + (kc2 + 1) * 16);
      nA1 = *(const longx2*)(pW2 + ((wave * 2 + 1) * 64 + lane) * 64 + (kc2 + 1) * 16);
    }
    longx2 b[4];
#pragma unroll
    for (int tt = 0; tt < 4; ++tt) {
      const int t = tt * 16 + l15;
      b[tt] = *(const longx2*)&Hs1[t * 256 + ((q * 64 + kc2 * 16) ^ SW2(t))];
    }
    __builtin_amdgcn_s_setprio(1);
#pragma unroll
    for (int s = 0; s < 2; ++s) {
#pragma unroll
      for (int tt = 0; tt < 4; ++tt) {
        acc[0][tt] = __builtin_amdgcn_mfma_f32_16x16x32_fp8_fp8(A0[s], b[tt][s], acc[0][tt], 0, 0, 0);
        acc[1][tt] = __builtin_amdgcn_mfma_f32_16x16x32_fp8_fp8(A1[s], b[tt][s], acc[1][tt], 0, 0, 0);
      }
    }
    __builtin_amdgcn_s_setprio(0);
    if (kc2 < 3) { A0 = nA0; A1 = nA1; }
  }
  // h2 -> Hs0 (x is dead: barrier (2) proved all x reads finished)
#pragma unroll
  for (int jt = 0; jt < 2; ++jt) {
    const int j0 = (wave * 2 + jt) * 16 + q * 4;
    const int pb = ((j0 >> 3) & 3) * 64 + (j0 >> 5) * 8 + (j0 & 7);
#pragma unroll
    for (int tt = 0; tt < 4; ++tt) {
      const int t = tt * 16 + l15;
      float v0 = fmaxf(acc[jt][tt][0], 0.f);
      float v1 = fmaxf(acc[jt][tt][1], 0.f);
      float v2 = fmaxf(acc[jt][tt][2], 0.f);
      float v3 = fmaxf(acc[jt][tt][3], 0.f);
      int u = __builtin_amdgcn_cvt_pk_fp8_f32(v0, v1, 0, false);
      u = __builtin_amdgcn_cvt_pk_fp8_f32(v2, v3, u, true);
      *(uint32_t*)&Hs0[t * 256 + (pb ^ SW2(t))] = (uint32_t)u;
    }
  }
  // prefetch L3 kc2=0 a-frags before the barrier
  longx2 C0 = *(const longx2*)(pW3 + ((wave * 2 + 0) * 64 + lane) * 64);
  longx2 C1 = *(const longx2*)(pW3 + ((wave * 2 + 1) * 64 + lane) * 64);
  __syncthreads();   // (3) h2 complete (implies all h1 reads done -> Hs1 dead)

  // ---- layer 3: K = 256 fp8, A = W3^T (fragment-major), B = h2(Hs0) ----
#pragma unroll
  for (int jt = 0; jt < 2; ++jt) {
    const float4 bb = *(const float4*)&b3[(wave * 2 + jt) * 16 + q * 4];
#pragma unroll
    for (int tt = 0; tt < 4; ++tt)
      acc[jt][tt] = (floatx4){bb.x, bb.y, bb.z, bb.w};
  }
#pragma unroll
  for (int kc2 = 0; kc2 < 4; ++kc2) {
    longx2 nC0, nC1;
    if (kc2 < 3) {
      nC0 = *(const longx2*)(pW3 + ((wave * 2 + 0) * 64 + lane) * 64 + (kc2 + 1) * 16);
      nC1 = *(const longx2*)(pW3 + ((wave * 2 + 1) * 64 + lane) * 64 + (kc2 + 1) * 16);
    }
    longx2 b[4];
#pragma unroll
    for (int tt = 0; tt < 4; ++tt) {
      const int t = tt * 16 + l15;
      b[tt] = *(const longx2*)&Hs0[t * 256 + ((q * 64 + kc2 * 16) ^ SW2(t))];
    }
    __builtin_amdgcn_s_setprio(1);
#pragma unroll
    for (int s = 0; s < 2; ++s) {
#pragma unroll
      for (int tt = 0; tt < 4; ++tt) {
        acc[0][tt] = __builtin_amdgcn_mfma_f32_16x16x32_fp8_fp8(C0[s], b[tt][s], acc[0][tt], 0, 0, 0);
        acc[1][tt] = __builtin_amdgcn_mfma_f32_16x16x32_fp8_fp8(C1[s], b[tt][s], acc[1][tt], 0, 0, 0);
      }
    }
    __builtin_amdgcn_s_setprio(0);
    if (kc2 < 3) { C0 = nC0; C1 = nC1; }
  }

  // relu + token-sum epilogue, scratch-based (no DS-pipe shuffles).
  {
    float4* scratch = (float4*)(HsAll + 16384);   // 64 rows x 17 float4
#pragma unroll
    for (int jt = 0; jt < 2; ++jt) {
      float s0 = 0.f, s1 = 0.f, s2 = 0.f, s3 = 0.f;
#pragma unroll
      for (int tt = 0; tt < 4; ++tt) {
        s0 += fmaxf(acc[jt][tt][0], 0.f);
        s1 += fmaxf(acc[jt][tt][1], 0.f);
        s2 += fmaxf(acc[jt][tt][2], 0.f);
        s3 += fmaxf(acc[jt][tt][3], 0.f);
      }
      scratch[((wave * 2 + jt) * 4 + q) * 17 + l15] = (float4){s0, s1, s2, s3};
    }
  }
  __syncthreads();   // (4) scratch ready
  if (tid < NHID) {
    // hidden j = tid: row = (j>>4)*4 + ((j>>2)&3), elem r = j&3
    const float* sf = (const float*)(HsAll + 16384);
    const int row = ((tid >> 4) << 2) + ((tid >> 2) & 3);
    const int r = tid & 3;
    float v = 0.f;
#pragma unroll
    for (int l = 0; l < 16; ++l)
      v += sf[row * 68 + l * 4 + r];
    atomicAdd(&msum[batch * NHID + tid], v);
  }
}

// ---------------------------------------------------------------------------
// Decoder: 256 blocks = (batch x d2-eighth), 1024 threads. Each block
// computes the full d1 (redundant x8, D1 is L2-resident), its 64-wide d2
// eighth, and atomicAdds its partial L3 dot into out (pre-init'd to c3).
// ---------------------------------------------------------------------------
__global__ __launch_bounds__(1024) void decoder(
    const float* __restrict__ msum,
    const float* __restrict__ D1, const float* __restrict__ c1,
    const float* __restrict__ D2, const float* __restrict__ c2,
    const float* __restrict__ D3,
    float* __restrict__ out) {
  __shared__ float p[NHID];
  __shared__ float d1[NDEC];
  __shared__ float d2e[64];
  __shared__ __align__(16) float red[4096];   // 16 KB
  const int b = blockIdx.x >> 3, qd = blockIdx.x & 7, t = threadIdx.x;

  if (t < NHID) {
    float m = msum[b * NHID + t] * (1.f / NTOK);
    p[t] = m * m;                        // relu(m^2) == m^2
  }
  __syncthreads();

  // ---- layer 1 (full, redundant x8): K = 256 -> 32 k per split ----
  {
    const int jg = t & 127;              // j-group of 4
    const int ks = t >> 7;               // 0..7 K-split
    const float4* D1v = (const float4*)D1;   // [256][128] float4
    float4 s = {0.f, 0.f, 0.f, 0.f};
    for (int k = ks * 32; k < ks * 32 + 32; ++k) {
      float4 w = D1v[k * 128 + jg];
      float pv = p[k];
      s.x += pv * w.x; s.y += pv * w.y; s.z += pv * w.z; s.w += pv * w.w;
    }
    *(float4*)&red[t * 4] = s;
    __syncthreads();
    if (t < NDEC) {
      float v = c1[t];
#pragma unroll
      for (int i = 0; i < 8; ++i) v += red[i * 512 + t];
      d1[t] = fmaxf(v, 0.f);
    }
    __syncthreads();
  }

  // ---- layer 2 (eighth): 64 outs, K = 512 -> 64 splits x 8 k ----
  {
    const int jg2 = t & 15;              // float4 group within eighth
    const int ks2 = t >> 4;              // 0..63 K-split
    const float4* D2v = (const float4*)D2;   // [512][128] float4
    float4 s = {0.f, 0.f, 0.f, 0.f};
    for (int k = ks2 * 8; k < ks2 * 8 + 8; ++k) {
      float4 w = D2v[k * 128 + qd * 16 + jg2];
      float hv = d1[k];
      s.x += hv * w.x; s.y += hv * w.y; s.z += hv * w.z; s.w += hv * w.w;
    }
    *(float4*)&red[t * 4] = s;           // == red[ks2*64 + jg2*4 + c]
    __syncthreads();
    if (t < 64) {
      float v = c2[qd * 64 + t];
#pragma unroll
      for (int i = 0; i < 64; ++i) v += red[i * 64 + t];
      d2e[t] = fmaxf(v, 0.f);
    }
    __syncthreads();
  }

  // ---- layer 3 partial: eighth K = 64; 64 k-chunks x 16 j-slots ----
  {
    const int j3 = t & 15;
    const int kc = t >> 4;               // 0..63, 1 k each
    float s = 0.f;
    if (j3 < NOUTC)
      s = d2e[kc] * D3[(qd * 64 + kc) * NOUTC + j3];
    red[t] = s;
    __syncthreads();
    if (t < NOUTC) {
      float v = 0.f;
#pragma unroll
      for (int i = 0; i < 64; ++i) v += red[i * 16 + t];
      atomicAdd(&out[b * NOUTC + t], v);
    }
  }
}

// ---------------------------------------------------------------------------
extern "C" void kernel_launch(void* const* d_in, const int* in_sizes, int n_in,
                              void* d_out, int out_size, void* d_ws, size_t ws_size,
                              hipStream_t stream) {
  const float* x  = (const float*)d_in[0];
  const float* W1 = (const float*)d_in[1];
  const float* b1 = (const float*)d_in[2];
  const float* W2 = (const float*)d_in[3];
  const float* b2 = (const float*)d_in[4];
  const float* W3 = (const float*)d_in[5];
  const float* b3 = (const float*)d_in[6];
  const float* D1 = (const float*)d_in[7];
  const float* c1 = (const float*)d_in[8];
  const float* D2 = (const float*)d_in[9];
  const float* c2 = (const float*)d_in[10];
  const float* D3 = (const float*)d_in[11];
  const float* c3 = (const float*)d_in[12];

  // ws: [0,64K) bf16 W1 | [64K,128K) fp8 W2 | [128K,192K) fp8 W3 |
  //     [384K,416K) msum
  uint8_t* pW   = (uint8_t*)d_ws;
  float*   msum = (float*)((char*)d_ws + 384 * 1024);

  pack_weights<<<640, 256, 0, stream>>>(W1, W2, W3, c3, pW, msum,
                                        (float*)d_out);
  encoder<<<NBLK, 512, 0, stream>>>(x, pW, b1, b2, b3, msum);
  decoder<<<256, 1024, 0, stream>>>(msum, D1, c1, D2, c2, D3,
                                    (float*)d_out);
}

// Round 13
// 150.753 us; speedup vs baseline: 1.1757x; 1.0112x over previous
//
#include <hip/hip_runtime.h>
#include <hip/hip_bf16.h>
#include <stdint.h>

// ---------------------------------------------------------------------------
// TensorNet: fused encoder MLP (128->256->256->256, relu) over 32x4096 tokens,
// per-batch mean -> p = relu(m^2) -> decoder MLP (256->512->512->10).
//
// R28: coalesced pack_weights (the last never-measured component). Old pack
// read W[k*NHID+m] with k varying across lanes -> 64 lines/wave 1KB apart
// (latency-bound scattered reads). New pack reads W[p] linearly (fully
// coalesced) and scatters only the WRITES (stores drain via L2, no stall).
// Index algebra is the exact inverse of the verified fragment layouts:
//   W1 (bf16, kc-major):  dest = ((mt*4+kc)*64+ln)*8 + j
//   W2/W3 (fp8, frag-major): dest = base + (mt*64+ln)*64 + kc*8 + j
//   with mt=m>>4, kc=k>>5, ln=((k&31)>>3)*16+(m&15), j=k&7.
// Encoder BYTE-IDENTICAL to R27 (best: 152.4us, encoder 45.7-50us);
// decoder byte-identical to R26. Clean A/B on pack.
//
// If this round is neutral (<=1us): all components are measured/optimized;
// declare structural convergence (encoder ~46us latency floor: serial
// 3-layer chain, 4 barriers, no pipe >50%; remainder harness-fixed).
//
// HARD RULES from the log:
//  - NEVER pass a min-waves arg to __launch_bounds__ (R5, R19, R22: spills).
//  - NEVER grow per-wave a-load count for "sharing" (R18: 185us).
//  - NEVER shrink MTILE / grow encoder block count (R20).
//  - Occupancy is NOT the encoder lever (R23); serial-chain latency and
//    LDS-pipe cycles are (R17, R24, R25, R27 — all predicted correctly).
// ---------------------------------------------------------------------------

#define NIN   128
#define NHID  256
#define NDEC  512
#define NOUTC 10
#define BATCH 32
#define NTOK  4096
#define MTILE 64
#define NBLK  (BATCH * (NTOK / MTILE))   // 2048 encoder tiles

#define SW2(t) (((t) & 15) << 4)         // XOR swizzle, byte bits 4-7

typedef short bf16x8 __attribute__((ext_vector_type(8)));
typedef float floatx4 __attribute__((ext_vector_type(4)));
typedef long  longx2  __attribute__((ext_vector_type(2)));

__device__ __forceinline__ uint16_t f2b(float f) {
  union { uint32_t u; float f; } v; v.f = f;
  uint32_t r = v.u + 0x7FFFu + ((v.u >> 16) & 1u);   // RNE
  return (uint16_t)(r >> 16);
}
__device__ __forceinline__ uint32_t pkbf(float lo, float hi) {
  __hip_bfloat162 h = __float22bfloat162_rn(float2{lo, hi});  // v_cvt_pk_bf16_f32
  union { __hip_bfloat162 h; uint32_t u; } c; c.h = h;
  return c.u;
}

// ---------------------------------------------------------------------------
// Pack weights, read-coalesced: thread p reads W?[p] linearly, computes the
// fragment-order destination, scattered-writes. Also zero-inits msum and
// pre-loads out with c3 (decoder atomics accumulate; stream-ordered).
// ---------------------------------------------------------------------------
__global__ __launch_bounds__(256) void pack_weights(
    const float* __restrict__ W1, const float* __restrict__ W2,
    const float* __restrict__ W3, const float* __restrict__ c3,
    uint8_t* __restrict__ pW, float* __restrict__ msum,
    float* __restrict__ out) {
  int p = blockIdx.x * blockDim.x + threadIdx.x;
  if (p < BATCH * NHID) msum[p] = 0.f;
  if (p < BATCH * NOUTC) out[p] = c3[p % NOUTC];
  if (p < 32768) {
    // W1: [128][256] row-major; p = k*256 + m. bf16, kc-major frags.
    int k = p >> 8, m = p & 255;
    int mt = m >> 4, l15 = m & 15;
    int kc = k >> 5, kk = k & 31;
    int ln = ((kk >> 3) << 4) + l15;
    int j  = kk & 7;
    ((uint16_t*)pW)[(((mt * 4 + kc) * 64 + ln) << 3) + j] = f2b(W1[p]);
  } else {
    int p2 = p - 32768;
    const float* W = (p2 < 65536) ? W2 : W3;
    int base = (p2 < 65536) ? 65536 : 131072;
    if (p2 >= 65536) p2 -= 65536;
    // W2/W3: [256][256] row-major; p2 = k*256 + m. fp8 e4m3, frag-major.
    int k = p2 >> 8, m = p2 & 255;
    int mt = m >> 4, l15 = m & 15;
    int kc = k >> 5, kk = k & 31;
    int ln = ((kk >> 3) << 4) + l15;
    int j  = kk & 7;
    int r = __builtin_amdgcn_cvt_pk_fp8_f32(W[p2], 0.f, 0, false);
    pW[base + (mt * 64 + ln) * 64 + kc * 8 + j] = (uint8_t)(r & 0xFF);
  }
}

// ---------------------------------------------------------------------------
// Fused encoder. Block = 512 thr (8 waves), 64 tokens. Wave w owns hidden
// rows [32w,32w+32). HsAll: [0,16K) x tile then h2; [16K,32K) h1; epilogue
// scratch overlays [16K,33792). 4 barriers. a-frags prefetched across each
// barrier + pipelined one kc ahead; setprio(1) around MFMA groups.
// (BYTE-IDENTICAL TO R27.)
// ---------------------------------------------------------------------------
__global__ __launch_bounds__(512) void encoder(
    const float* __restrict__ x,        // [BATCH*NTOK][NIN] fp32
    const uint8_t* __restrict__ pW,
    const float* __restrict__ b1,
    const float* __restrict__ b2,
    const float* __restrict__ b3,
    float* __restrict__ msum) {         // [BATCH][NHID] fp32 accum
  __shared__ __align__(16) uint8_t HsAll[33792];
  uint8_t* Hs0 = HsAll;                 // 16384 B: x (bf16), then h2 (fp8)
  uint8_t* Hs1 = HsAll + 16384;         // 16384 B: h1 (fp8)

  const int tid  = threadIdx.x;
  const int wave = tid >> 6;
  const int lane = tid & 63;
  const int l15  = lane & 15;
  const int q    = lane >> 4;
  const int tok0  = blockIdx.x * MTILE;
  const int batch = blockIdx.x >> 6;          // 64 tiles per batch

  const uint16_t* pW1 = (const uint16_t*)pW;  // bf16 frags, KC=4
  const uint8_t*  pW2 = pW + 65536;           // fp8 frags, fragment-major
  const uint8_t*  pW3 = pW + 131072;          // fp8 frags, fragment-major

  // ---- stage x tile: 64 tok x 128 ch fp32 -> bf16, row 256B, SW2 ----
  {
    const float4* xv = (const float4*)(x + (size_t)tok0 * NIN);
#pragma unroll
    for (int i = 0; i < 2; ++i) {
      const int u = tid + i * 512;            // 8-float unit, 0..1023
      float4 va = xv[2 * u];
      float4 vb = xv[2 * u + 1];
      uint4 w = make_uint4(pkbf(va.x, va.y), pkbf(va.z, va.w),
                           pkbf(vb.x, vb.y), pkbf(vb.z, vb.w));
      const int row = u >> 4;                 // token 0..63
      const int cb  = (u & 15) << 4;          // byte col 0..240
      *(uint4*)&Hs0[row * 256 + (cb ^ SW2(row))] = w;
    }
  }
  // prefetch L1 kc=0 a-frags before the barrier (pW-only dependency)
  bf16x8 a0 = *(const bf16x8*)(pW1 + ((((wave * 2 + 0) * 4 + 0) * 64 + lane) << 3));
  bf16x8 a1 = *(const bf16x8*)(pW1 + ((((wave * 2 + 1) * 4 + 0) * 64 + lane) << 3));
  __syncthreads();   // (1) x staged

  floatx4 acc[2][4];   // [jt][tt]

  // ---- layer 1: K = 128 bf16, A = W1^T, B = x(Hs0); acc init = bias ----
#pragma unroll
  for (int jt = 0; jt < 2; ++jt) {
    const float4 bb = *(const float4*)&b1[(wave * 2 + jt) * 16 + q * 4];
#pragma unroll
    for (int tt = 0; tt < 4; ++tt)
      acc[jt][tt] = (floatx4){bb.x, bb.y, bb.z, bb.w};
  }
#pragma unroll
  for (int kc = 0; kc < 4; ++kc) {
    bf16x8 na0, na1;
    if (kc < 3) {
      na0 = *(const bf16x8*)(pW1 + ((((wave * 2 + 0) * 4 + kc + 1) * 64 + lane) << 3));
      na1 = *(const bf16x8*)(pW1 + ((((wave * 2 + 1) * 4 + kc + 1) * 64 + lane) << 3));
    }
    bf16x8 b[4];
#pragma unroll
    for (int tt = 0; tt < 4; ++tt) {
      const int t = tt * 16 + l15;
      b[tt] = *(const bf16x8*)&Hs0[t * 256 + ((kc * 64 + q * 16) ^ SW2(t))];
    }
    __builtin_amdgcn_s_setprio(1);
#pragma unroll
    for (int tt = 0; tt < 4; ++tt) {
      acc[0][tt] = __builtin_amdgcn_mfma_f32_16x16x32_bf16(a0, b[tt], acc[0][tt], 0, 0, 0);
      acc[1][tt] = __builtin_amdgcn_mfma_f32_16x16x32_bf16(a1, b[tt], acc[1][tt], 0, 0, 0);
    }
    __builtin_amdgcn_s_setprio(0);
    if (kc < 3) { a0 = na0; a1 = na1; }
  }
  // h1 -> Hs1 (fragment-major fp8); no barrier needed (different buffer)
#pragma unroll
  for (int jt = 0; jt < 2; ++jt) {
    const int j0 = (wave * 2 + jt) * 16 + q * 4;
    const int pb = ((j0 >> 3) & 3) * 64 + (j0 >> 5) * 8 + (j0 & 7);
#pragma unroll
    for (int tt = 0; tt < 4; ++tt) {
      const int t = tt * 16 + l15;
      float v0 = fmaxf(acc[jt][tt][0], 0.f);
      float v1 = fmaxf(acc[jt][tt][1], 0.f);
      float v2 = fmaxf(acc[jt][tt][2], 0.f);
      float v3 = fmaxf(acc[jt][tt][3], 0.f);
      int u = __builtin_amdgcn_cvt_pk_fp8_f32(v0, v1, 0, false);
      u = __builtin_amdgcn_cvt_pk_fp8_f32(v2, v3, u, true);
      *(uint32_t*)&Hs1[t * 256 + (pb ^ SW2(t))] = (uint32_t)u;
    }
  }
  // prefetch L2 kc2=0 a-frags before the barrier
  longx2 A0 = *(const longx2*)(pW2 + ((wave * 2 + 0) * 64 + lane) * 64);
  longx2 A1 = *(const longx2*)(pW2 + ((wave * 2 + 1) * 64 + lane) * 64);
  __syncthreads();   // (2) h1 complete (implies all x reads done too)

  // ---- layer 2: K = 256 fp8, A = W2^T (fragment-major), B = h1(Hs1) ----
#pragma unroll
  for (int jt = 0; jt < 2; ++jt) {
    const float4 bb = *(const float4*)&b2[(wave * 2 + jt) * 16 + q * 4];
#pragma unroll
    for (int tt = 0; tt < 4; ++tt)
      acc[jt][tt] = (floatx4){bb.x, bb.y, bb.z, bb.w};
  }
#pragma unroll
  for (int kc2 = 0; kc2 < 4; ++kc2) {
    longx2 nA0, nA1;
    if (kc2 < 3) {
      nA0 = *(const longx2*)(pW2 + ((wave * 2 + 0) * 64 + lane) * 64 + (kc2 + 1) * 16);
      nA1 = *(const longx2*)(pW2 + ((wave * 2 + 1) * 64 + lane) * 64 + (kc2 + 1) * 16);
    }
    longx2 b[4];
#pragma unroll
    for (int tt = 0; tt < 4; ++tt) {
      const int t = tt * 16 + l15;
      b[tt] = *(const longx2*)&Hs1[t * 256 + ((q * 64 + kc2 * 16) ^ SW2(t))];
    }
    __builtin_amdgcn_s_setprio(1);
#pragma unroll
    for (int s = 0; s < 2; ++s) {
#pragma unroll
      for (int tt = 0; tt < 4; ++tt) {
        acc[0][tt] = __builtin_amdgcn_mfma_f32_16x16x32_fp8_fp8(A0[s], b[tt][s], acc[0][tt], 0, 0, 0);
        acc[1][tt] = __builtin_amdgcn_mfma_f32_16x16x32_fp8_fp8(A1[s], b[tt][s], acc[1][tt], 0, 0, 0);
      }
    }
    __builtin_amdgcn_s_setprio(0);
    if (kc2 < 3) { A0 = nA0; A1 = nA1; }
  }
  // h2 -> Hs0 (x is dead: barrier (2) proved all x reads finished)
#pragma unroll
  for (int jt = 0; jt < 2; ++jt) {
    const int j0 = (wave * 2 + jt) * 16 + q * 4;
    const int pb = ((j0 >> 3) & 3) * 64 + (j0 >> 5) * 8 + (j0 & 7);
#pragma unroll
    for (int tt = 0; tt < 4; ++tt) {
      const int t = tt * 16 + l15;
      float v0 = fmaxf(acc[jt][tt][0], 0.f);
      float v1 = fmaxf(acc[jt][tt][1], 0.f);
      float v2 = fmaxf(acc[jt][tt][2], 0.f);
      float v3 = fmaxf(acc[jt][tt][3], 0.f);
      int u = __builtin_amdgcn_cvt_pk_fp8_f32(v0, v1, 0, false);
      u = __builtin_amdgcn_cvt_pk_fp8_f32(v2, v3, u, true);
      *(uint32_t*)&Hs0[t * 256 + (pb ^ SW2(t))] = (uint32_t)u;
    }
  }
  // prefetch L3 kc2=0 a-frags before the barrier
  longx2 C0 = *(const longx2*)(pW3 + ((wave * 2 + 0) * 64 + lane) * 64);
  longx2 C1 = *(const longx2*)(pW3 + ((wave * 2 + 1) * 64 + lane) * 64);
  __syncthreads();   // (3) h2 complete (implies all h1 reads done -> Hs1 dead)

  // ---- layer 3: K = 256 fp8, A = W3^T (fragment-major), B = h2(Hs0) ----
#pragma unroll
  for (int jt = 0; jt < 2; ++jt) {
    const float4 bb = *(const float4*)&b3[(wave * 2 + jt) * 16 + q * 4];
#pragma unroll
    for (int tt = 0; tt < 4; ++tt)
      acc[jt][tt] = (floatx4){bb.x, bb.y, bb.z, bb.w};
  }
#pragma unroll
  for (int kc2 = 0; kc2 < 4; ++kc2) {
    longx2 nC0, nC1;
    if (kc2 < 3) {
      nC0 = *(const longx2*)(pW3 + ((wave * 2 + 0) * 64 + lane) * 64 + (kc2 + 1) * 16);
      nC1 = *(const longx2*)(pW3 + ((wave * 2 + 1) * 64 + lane) * 64 + (kc2 + 1) * 16);
    }
    longx2 b[4];
#pragma unroll
    for (int tt = 0; tt < 4; ++tt) {
      const int t = tt * 16 + l15;
      b[tt] = *(const longx2*)&Hs0[t * 256 + ((q * 64 + kc2 * 16) ^ SW2(t))];
    }
    __builtin_amdgcn_s_setprio(1);
#pragma unroll
    for (int s = 0; s < 2; ++s) {
#pragma unroll
      for (int tt = 0; tt < 4; ++tt) {
        acc[0][tt] = __builtin_amdgcn_mfma_f32_16x16x32_fp8_fp8(C0[s], b[tt][s], acc[0][tt], 0, 0, 0);
        acc[1][tt] = __builtin_amdgcn_mfma_f32_16x16x32_fp8_fp8(C1[s], b[tt][s], acc[1][tt], 0, 0, 0);
      }
    }
    __builtin_amdgcn_s_setprio(0);
    if (kc2 < 3) { C0 = nC0; C1 = nC1; }
  }

  // relu + token-sum epilogue, scratch-based (no DS-pipe shuffles).
  {
    float4* scratch = (float4*)(HsAll + 16384);   // 64 rows x 17 float4
#pragma unroll
    for (int jt = 0; jt < 2; ++jt) {
      float s0 = 0.f, s1 = 0.f, s2 = 0.f, s3 = 0.f;
#pragma unroll
      for (int tt = 0; tt < 4; ++tt) {
        s0 += fmaxf(acc[jt][tt][0], 0.f);
        s1 += fmaxf(acc[jt][tt][1], 0.f);
        s2 += fmaxf(acc[jt][tt][2], 0.f);
        s3 += fmaxf(acc[jt][tt][3], 0.f);
      }
      scratch[((wave * 2 + jt) * 4 + q) * 17 + l15] = (float4){s0, s1, s2, s3};
    }
  }
  __syncthreads();   // (4) scratch ready
  if (tid < NHID) {
    // hidden j = tid: row = (j>>4)*4 + ((j>>2)&3), elem r = j&3
    const float* sf = (const float*)(HsAll + 16384);
    const int row = ((tid >> 4) << 2) + ((tid >> 2) & 3);
    const int r = tid & 3;
    float v = 0.f;
#pragma unroll
    for (int l = 0; l < 16; ++l)
      v += sf[row * 68 + l * 4 + r];
    atomicAdd(&msum[batch * NHID + tid], v);
  }
}

// ---------------------------------------------------------------------------
// Decoder: 256 blocks = (batch x d2-eighth), 1024 threads. Each block
// computes the full d1 (redundant x8, D1 is L2-resident), its 64-wide d2
// eighth, and atomicAdds its partial L3 dot into out (pre-init'd to c3).
// (BYTE-IDENTICAL TO R26.)
// ---------------------------------------------------------------------------
__global__ __launch_bounds__(1024) void decoder(
    const float* __restrict__ msum,
    const float* __restrict__ D1, const float* __restrict__ c1,
    const float* __restrict__ D2, const float* __restrict__ c2,
    const float* __restrict__ D3,
    float* __restrict__ out) {
  __shared__ float p[NHID];
  __shared__ float d1[NDEC];
  __shared__ float d2e[64];
  __shared__ __align__(16) float red[4096];   // 16 KB
  const int b = blockIdx.x >> 3, qd = blockIdx.x & 7, t = threadIdx.x;

  if (t < NHID) {
    float m = msum[b * NHID + t] * (1.f / NTOK);
    p[t] = m * m;                        // relu(m^2) == m^2
  }
  __syncthreads();

  // ---- layer 1 (full, redundant x8): K = 256 -> 32 k per split ----
  {
    const int jg = t & 127;              // j-group of 4
    const int ks = t >> 7;               // 0..7 K-split
    const float4* D1v = (const float4*)D1;   // [256][128] float4
    float4 s = {0.f, 0.f, 0.f, 0.f};
    for (int k = ks * 32; k < ks * 32 + 32; ++k) {
      float4 w = D1v[k * 128 + jg];
      float pv = p[k];
      s.x += pv * w.x; s.y += pv * w.y; s.z += pv * w.z; s.w += pv * w.w;
    }
    *(float4*)&red[t * 4] = s;
    __syncthreads();
    if (t < NDEC) {
      float v = c1[t];
#pragma unroll
      for (int i = 0; i < 8; ++i) v += red[i * 512 + t];
      d1[t] = fmaxf(v, 0.f);
    }
    __syncthreads();
  }

  // ---- layer 2 (eighth): 64 outs, K = 512 -> 64 splits x 8 k ----
  {
    const int jg2 = t & 15;              // float4 group within eighth
    const int ks2 = t >> 4;              // 0..63 K-split
    const float4* D2v = (const float4*)D2;   // [512][128] float4
    float4 s = {0.f, 0.f, 0.f, 0.f};
    for (int k = ks2 * 8; k < ks2 * 8 + 8; ++k) {
      float4 w = D2v[k * 128 + qd * 16 + jg2];
      float hv = d1[k];
      s.x += hv * w.x; s.y += hv * w.y; s.z += hv * w.z; s.w += hv * w.w;
    }
    *(float4*)&red[t * 4] = s;           // == red[ks2*64 + jg2*4 + c]
    __syncthreads();
    if (t < 64) {
      float v = c2[qd * 64 + t];
#pragma unroll
      for (int i = 0; i < 64; ++i) v += red[i * 64 + t];
      d2e[t] = fmaxf(v, 0.f);
    }
    __syncthreads();
  }

  // ---- layer 3 partial: eighth K = 64; 64 k-chunks x 16 j-slots ----
  {
    const int j3 = t & 15;
    const int kc = t >> 4;               // 0..63, 1 k each
    float s = 0.f;
    if (j3 < NOUTC)
      s = d2e[kc] * D3[(qd * 64 + kc) * NOUTC + j3];
    red[t] = s;
    __syncthreads();
    if (t < NOUTC) {
      float v = 0.f;
#pragma unroll
      for (int i = 0; i < 64; ++i) v += red[i * 16 + t];
      atomicAdd(&out[b * NOUTC + t], v);
    }
  }
}

// ---------------------------------------------------------------------------
extern "C" void kernel_launch(void* const* d_in, const int* in_sizes, int n_in,
                              void* d_out, int out_size, void* d_ws, size_t ws_size,
                              hipStream_t stream) {
  const float* x  = (const float*)d_in[0];
  const float* W1 = (const float*)d_in[1];
  const float* b1 = (const float*)d_in[2];
  const float* W2 = (const float*)d_in[3];
  const float* b2 = (const float*)d_in[4];
  const float* W3 = (const float*)d_in[5];
  const float* b3 = (const float*)d_in[6];
  const float* D1 = (const float*)d_in[7];
  const float* c1 = (const float*)d_in[8];
  const float* D2 = (const float*)d_in[9];
  const float* c2 = (const float*)d_in[10];
  const float* D3 = (const float*)d_in[11];
  const float* c3 = (const float*)d_in[12];

  // ws: [0,64K) bf16 W1 | [64K,128K) fp8 W2 | [128K,192K) fp8 W3 |
  //     [384K,416K) msum
  uint8_t* pW   = (uint8_t*)d_ws;
  float*   msum = (float*)((char*)d_ws + 384 * 1024);

  pack_weights<<<640, 256, 0, stream>>>(W1, W2, W3, c3, pW, msum,
                                        (float*)d_out);
  encoder<<<NBLK, 512, 0, stream>>>(x, pW, b1, b2, b3, msum);
  decoder<<<256, 1024, 0, stream>>>(msum, D1, c1, D2, c2, D3,
                                    (float*)d_out);
}